// Round 1
// baseline (17420.015 us; speedup 1.0000x reference)
//
#include <hip/hip_runtime.h>
#include <math.h>

#define T_STEPS 8
#define NN 50000
#define EE 800000
#define TN (T_STEPS*NN)   // 400000
#define TE (T_STEPS*EE)   // 6400000

__device__ __forceinline__ float sigf(float x){ return 1.0f/(1.0f+expf(-x)); }

__device__ __forceinline__ float wred64(float v){
#pragma unroll
  for(int o=32;o>0;o>>=1) v += __shfl_xor(v, o);
  return v;
}

// ---------------- generic fp32 GEMM: C = act((A@W)*scale + bias) ----------------
struct ASegs { const float* p0; const float* p1; const float* p2; int w0,w1,w2; };

__device__ __forceinline__ float loadA(const ASegs& A, int r, int k){
  if (k < A.w0) return A.p0[(size_t)r*A.w0 + k];
  k -= A.w0;
  if (k < A.w1) return A.p1[(size_t)r*A.w1 + k];
  k -= A.w1;
  return A.p2[(size_t)r*A.w2 + k];
}

template<bool WT>  // WT: W layout [NO,K] (row-major out,in); else [K,NO]
__global__ __launch_bounds__(256) void gemm_k(ASegs A, const float* __restrict__ W,
    const float* __restrict__ bias, const float* __restrict__ scale,
    float* __restrict__ C, int Nrow, int K, int NO, int ldc, int act)
{
  constexpr int BM=64, BN=128, BK=16;
  __shared__ __align__(16) float As[BK][BM+4];
  __shared__ __align__(16) float Ws[BK][BN+4];
  const int tid  = threadIdx.x;
  const int brow = blockIdx.x*BM;
  const int bcol = blockIdx.y*BN;
  const int r0 = (tid>>4)*4;
  const int c0 = (tid&15)*8;
  float acc[4][8];
#pragma unroll
  for(int i=0;i<4;i++)
#pragma unroll
    for(int j=0;j<8;j++) acc[i][j]=0.f;

  for (int k0=0; k0<K; k0+=BK){
    { // stage A (64 x 16)
      int r  = tid>>2;
      int ks = (tid&3)*4;
      int gr = brow + r;
#pragma unroll
      for (int i=0;i<4;i++){
        int gk = k0+ks+i;
        float v = 0.f;
        if (gr < Nrow && gk < K) v = loadA(A, gr, gk);
        As[ks+i][r] = v;
      }
    }
    if (WT) { // stage W (16 x 128) from [NO,K]
#pragma unroll
      for (int it=0; it<8; ++it){
        int idx = tid + it*256;
        int c = idx>>4;
        int k = idx&15;
        int gc = bcol+c, gk = k0+k;
        float v=0.f;
        if (gc<NO && gk<K) v = W[(size_t)gc*K + gk];
        Ws[k][c]=v;
      }
    } else {  // from [K,NO]
#pragma unroll
      for (int it=0; it<8; ++it){
        int idx = tid + it*256;
        int k = idx>>7;
        int c = idx&127;
        int gc = bcol+c, gk = k0+k;
        float v=0.f;
        if (gc<NO && gk<K) v = W[(size_t)gk*NO + gc];
        Ws[k][c]=v;
      }
    }
    __syncthreads();
#pragma unroll
    for (int kk=0;kk<BK;kk++){
      const float4 av  = *(const float4*)&As[kk][r0];
      const float4 w0v = *(const float4*)&Ws[kk][c0];
      const float4 w1v = *(const float4*)&Ws[kk][c0+4];
      float a[4]={av.x,av.y,av.z,av.w};
      float w[8]={w0v.x,w0v.y,w0v.z,w0v.w,w1v.x,w1v.y,w1v.z,w1v.w};
#pragma unroll
      for(int i=0;i<4;i++)
#pragma unroll
        for(int j=0;j<8;j++)
          acc[i][j] = fmaf(a[i], w[j], acc[i][j]);
    }
    __syncthreads();
  }
#pragma unroll
  for(int i=0;i<4;i++){
    int r = brow + r0 + i;
    if (r >= Nrow) continue;
#pragma unroll
    for(int j=0;j<8;j++){
      int c = bcol + c0 + j;
      if (c >= NO) continue;
      float v = acc[i][j];
      if (scale) v *= scale[c];
      if (bias)  v += bias[c];
      if (act==1) v = fmaxf(v, 0.f);
      else if (act==2) v = sigf(v);
      C[(size_t)r*ldc + c] = v;
    }
  }
}

// ---------------- CSR build ----------------
__global__ void count_k(const int* __restrict__ ei, const float* __restrict__ ewl,
                        int* __restrict__ cnt, float* __restrict__ degw)
{
  int idx = blockIdx.x*256 + threadIdx.x;
  if (idx >= TE) return;
  int t = idx / EE;
  int e = idx - t*EE;
  const int* dst = ei + (size_t)t*2*EE + EE;
  int d = dst[e];
  atomicAdd(&cnt[t*NN + d], 1);
  atomicAdd(&degw[t*NN + d], sigf(ewl[idx]));
}

__global__ void scan1_k(const int* __restrict__ in, int* __restrict__ outv,
                        int* __restrict__ partials, int n)
{
  __shared__ int sh[256];
  int base = blockIdx.x*1024;
  int tid = threadIdx.x;
  int v[4]; int s=0;
#pragma unroll
  for (int i=0;i<4;i++){ int idx=base+tid*4+i; v[i] = (idx<n)? in[idx]:0; s+=v[i]; }
  sh[tid]=s; __syncthreads();
  for (int o=1;o<256;o<<=1){
    int t2 = (tid>=o)? sh[tid-o]:0;
    __syncthreads();
    sh[tid]+=t2;
    __syncthreads();
  }
  int excl = sh[tid]-s;
#pragma unroll
  for (int i=0;i<4;i++){ int idx=base+tid*4+i; if(idx<n) outv[idx]=excl; excl+=v[i]; }
  if (tid==255) partials[blockIdx.x]=sh[255];
}

__global__ void scan2_k(int* p, int np){
  __shared__ int sh[256];
  __shared__ int run;
  int tid=threadIdx.x;
  if(tid==0) run=0;
  __syncthreads();
  for(int base=0;base<np;base+=256){
    int v = (base+tid<np)? p[base+tid]:0;
    sh[tid]=v; __syncthreads();
    for(int o=1;o<256;o<<=1){
      int t2 = (tid>=o)? sh[tid-o]:0;
      __syncthreads();
      sh[tid]+=t2;
      __syncthreads();
    }
    int incl=sh[tid];
    int r0=run;
    __syncthreads();
    if(base+tid<np) p[base+tid]=r0+incl-v;
    __syncthreads();
    if(tid==0) run = r0 + sh[255];
    __syncthreads();
  }
}

__global__ void scan3_k(int* __restrict__ offs, const int* __restrict__ parts,
                        int* __restrict__ cur, int n){
  int idx = blockIdx.x*256+threadIdx.x;
  if (idx==0) offs[n] = TE;
  if (idx<n){ int v = offs[idx] + parts[idx>>10]; offs[idx]=v; cur[idx]=v; }
}

__global__ void dinv_k(const float* __restrict__ degw, float* __restrict__ dnv,
                       float* __restrict__ invd){
  int idx = blockIdx.x*256+threadIdx.x;
  if (idx>=TN) return;
  float dv = degw[idx]+1.f;
  dnv[idx]  = rsqrtf(dv);
  invd[idx] = 1.f/dv;
}

__global__ void fill_k(const int* __restrict__ ei, const float* __restrict__ ewl,
                       const float* __restrict__ dnv, int* __restrict__ cur,
                       int* __restrict__ esrc, float* __restrict__ enorm)
{
  int idx = blockIdx.x*256 + threadIdx.x;
  if (idx >= TE) return;
  int t = idx / EE;
  int e = idx - t*EE;
  const int* srcp = ei + (size_t)t*2*EE;
  const int* dstp = srcp + EE;
  int s=srcp[e], d=dstp[e];
  float nr = dnv[t*NN+s] * sigf(ewl[idx]) * dnv[t*NN+d];
  int pos = atomicAdd(&cur[t*NN+d], 1);
  esrc[pos]=s; enorm[pos]=nr;
}

// ---------------- GCN gather: rep = relu(agg + xw/deg + b) ----------------
__global__ __launch_bounds__(256) void gather_k(const int* __restrict__ offs_t,
    const int* __restrict__ esrc, const float* __restrict__ enorm,
    const float* __restrict__ xw, const float* __restrict__ invd_t,
    const float* __restrict__ gcb_t, float* __restrict__ rep)
{
  int node = blockIdx.x*4 + (threadIdx.x>>6);
  int lane = threadIdx.x & 63;
  if (node >= NN) return;
  int o0 = offs_t[node], o1 = offs_t[node+1];
  float a0=0.f, a1=0.f;
  for (int j=o0;j<o1;++j){
    int s = esrc[j];
    float nr = enorm[j];
    const float* xr = xw + (size_t)s*128;
    a0 = fmaf(nr, xr[lane],    a0);
    a1 = fmaf(nr, xr[64+lane], a1);
  }
  float sl = invd_t[node];
  const float* xs = xw + (size_t)node*128;
  a0 = fmaf(sl, xs[lane],    a0) + gcb_t[lane];
  a1 = fmaf(sl, xs[64+lane], a1) + gcb_t[64+lane];
  rep[(size_t)node*128+lane]    = fmaxf(a0,0.f);
  rep[(size_t)node*128+64+lane] = fmaxf(a1,0.f);
}

// ---------------- GRU pointwise ----------------
__global__ void gru_k(const float* __restrict__ gi, const float* __restrict__ gh,
                      const float* __restrict__ h, float* __restrict__ hout)
{
  int idx = blockIdx.x*256+threadIdx.x;   // < NN*256
  int node = idx>>8; int j = idx&255;
  size_t b=(size_t)node*768;
  float r  = sigf(gi[b+j]     + gh[b+j]);
  float u  = sigf(gi[b+256+j] + gh[b+256+j]);
  float nn = tanhf(gi[b+512+j] + r*gh[b+512+j]);
  hout[idx] = (1.f-u)*nn + u*h[idx];
}

// ---------------- heads ----------------
__global__ __launch_bounds__(256) void heads_dot_k(const float* __restrict__ u2,
    const float* __restrict__ w01, const float* __restrict__ b01,
    const float* __restrict__ w11, const float* __restrict__ b11,
    float* __restrict__ y0out, float* __restrict__ y1out)
{
  int node = blockIdx.x*4 + (threadIdx.x>>6);
  int lane = threadIdx.x&63;
  if (node>=NN) return;
  const float* row = u2 + (size_t)node*256;
  float a0 = row[lane]*w01[lane]     + row[64+lane]*w01[64+lane];
  float a1 = row[128+lane]*w11[lane] + row[192+lane]*w11[64+lane];
  a0 = wred64(a0); a1 = wred64(a1);
  if (lane==0){ y0out[node]=a0+b01[0]; y1out[node]=a1+b11[0]; }
}

__global__ __launch_bounds__(256) void ps2_k(const float* __restrict__ sbuf,
    const float* __restrict__ W2, const float* __restrict__ b2,
    float* __restrict__ psout)
{
  int node = blockIdx.x*4+(threadIdx.x>>6);
  int lane=threadIdx.x&63;
  if(node>=NN) return;
  const float* srow = sbuf + (size_t)node*100;
  float a0=0.f,a1=0.f;
  for (int f=lane; f<100; f+=64){
    float sv=srow[f];
    a0 += sv*W2[2*f]; a1 += sv*W2[2*f+1];
  }
  a0=wred64(a0); a1=wred64(a1);
  if(lane==0){
    float l0=a0+b2[0], l1=a1+b2[1];
    float m=fmaxf(l0,l1);
    float e0=expf(l0-m), e1=expf(l1-m);
    float inv=1.f/(e0+e1);
    psout[(size_t)node*2]   = e0*inv;
    psout[(size_t)node*2+1] = e1*inv;
  }
}

// ---------------- weight prep ----------------
__global__ void wprep_k(const float* __restrict__ o00W,const float* __restrict__ o10W,
    const float* __restrict__ o00b,const float* __restrict__ o10b,
    const float* __restrict__ ps1b,const float* __restrict__ bng,const float* __restrict__ bnb,
    float* __restrict__ woc,float* __restrict__ b2,float* __restrict__ psc,float* __restrict__ psb)
{
  int i = blockIdx.x*256+threadIdx.x;
  if (i < 128*256){
    int k=i>>8, o=i&255;
    woc[i] = (o<128)? o00W[k*128+o] : o10W[k*128+o-128];
  }
  if (i<256) b2[i] = (i<128)? o00b[i] : o10b[i-128];
  if (i<100){ float sc = bng[i]*rsqrtf(1.f+1e-5f); psc[i]=sc; psb[i]=ps1b[i]*sc+bnb[i]; }
}

extern "C" void kernel_launch(void* const* d_in, const int* in_sizes, int n_in,
                              void* d_out_v, int out_size, void* d_ws, size_t ws_size,
                              hipStream_t stream)
{
  const float* X    = (const float*)d_in[0];
  const float* Cc   = (const float*)d_in[1];
  const float* Yh   = (const float*)d_in[2];
  const int*   EI   = (const int*)  d_in[3];
  const float* phiW = (const float*)d_in[4];  const float* phib = (const float*)d_in[5];
  const float* gcW  = (const float*)d_in[6];  const float* gcb  = (const float*)d_in[7];
  const float* ewl  = (const float*)d_in[8];
  const float* fuseW= (const float*)d_in[9];  const float* fuseb= (const float*)d_in[10];
  const float* o00W = (const float*)d_in[11]; const float* o00b = (const float*)d_in[12];
  const float* o10W = (const float*)d_in[13]; const float* o10b = (const float*)d_in[14];
  const float* o01W = (const float*)d_in[15]; const float* o01b = (const float*)d_in[16];
  const float* o11W = (const float*)d_in[17]; const float* o11b = (const float*)d_in[18];
  const float* ps1W = (const float*)d_in[19]; const float* ps1b = (const float*)d_in[20];
  const float* bng  = (const float*)d_in[21]; const float* bnb  = (const float*)d_in[22];
  const float* ps2W = (const float*)d_in[23]; const float* ps2b = (const float*)d_in[24];
  const float* Wih  = (const float*)d_in[25]; const float* Whh  = (const float*)d_in[26];
  const float* bih  = (const float*)d_in[27]; const float* bhh  = (const float*)d_in[28];
  float* out = (float*)d_out_v;

  char* wsb = (char*)d_ws;
  size_t off=0;
  auto alloc=[&](size_t bytes)->void*{
    void* p = wsb + off;
    off = (off + bytes + 255) & ~(size_t)255;
    return p;
  };
  int*   cnt   = (int*)  alloc((size_t)TN*4);
  int*   cur   = (int*)  alloc((size_t)TN*4);
  int*   offs  = (int*)  alloc(((size_t)TN+1)*4);
  float* degw  = (float*)alloc((size_t)TN*4);
  float* dnv   = (float*)alloc((size_t)TN*4);
  float* invd  = (float*)alloc((size_t)TN*4);
  int*   esrc  = (int*)  alloc((size_t)TE*4);
  float* enorm = (float*)alloc((size_t)TE*4);
  int*   parts = (int*)  alloc(4096);
  float* phi   = (float*)alloc((size_t)NN*256*4);
  float* xw    = (float*)alloc((size_t)NN*128*4);
  float* rep   = (float*)alloc((size_t)NN*128*4);
  float* hb0   = (float*)alloc((size_t)NN*256*4);
  float* hb1   = (float*)alloc((size_t)NN*256*4);
  float* gi    = (float*)alloc((size_t)NN*768*4);
  float* gh    = (float*)alloc((size_t)NN*768*4);
  float* woc   = (float*)alloc(128*256*4);
  float* b2    = (float*)alloc(256*4);
  float* psc   = (float*)alloc(100*4);
  float* psb   = (float*)alloc(100*4);
  float* u2    = gi;   // reused after gru consumes gi/gh
  float* sbuf  = gh;

  hipMemsetAsync(cnt,  0, (size_t)TN*4, stream);
  hipMemsetAsync(degw, 0, (size_t)TN*4, stream);
  hipMemsetAsync(hb0,  0, (size_t)NN*256*4, stream);

  wprep_k<<<128,256,0,stream>>>(o00W,o10W,o00b,o10b,ps1b,bng,bnb,woc,b2,psc,psb);
  count_k<<<(TE+255)/256,256,0,stream>>>(EI,ewl,cnt,degw);
  scan1_k<<<(TN+1023)/1024,256,0,stream>>>(cnt,offs,parts,TN);
  scan2_k<<<1,256,0,stream>>>(parts,(TN+1023)/1024);
  scan3_k<<<(TN+255)/256,256,0,stream>>>(offs,parts,cur,TN);
  dinv_k<<<(TN+255)/256,256,0,stream>>>(degw,dnv,invd);
  fill_k<<<(TE+255)/256,256,0,stream>>>(EI,ewl,dnv,cur,esrc,enorm);

  const size_t zoff  = (size_t)2*TN;               // 800000
  const size_t psoff = zoff + (size_t)TN*128;      // 52,000,000
  const size_t hoff  = psoff + (size_t)TN*2;       // 52,800,000
  constexpr int GB = (NN+63)/64;                   // 782

  for (int t=0;t<T_STEPS;t++){
    const float* hin = (t&1)? hb1: hb0;
    float* hout = (t==T_STEPS-1)? (out+hoff) : ((t&1)? hb0: hb1);
    float* zt = out + zoff + (size_t)t*NN*128;

    // phi = relu(X_t @ phi_W + phi_b)
    gemm_k<false><<<dim3(GB,2),256,0,stream>>>(
      ASegs{X+(size_t)t*NN*128,nullptr,nullptr,128,0,0}, phiW, phib, nullptr,
      phi, NN,128,256,256,1);
    // xw = phi @ gc_W[t]
    gemm_k<false><<<dim3(GB,1),256,0,stream>>>(
      ASegs{phi,nullptr,nullptr,256,0,0}, gcW+(size_t)t*256*128, nullptr, nullptr,
      xw, NN,256,128,128,0);
    // rep = relu(agg + xw/deg + gc_b[t])
    gather_k<<<NN/4,256,0,stream>>>(offs+(size_t)t*NN, esrc, enorm, xw,
                                    invd+(size_t)t*NN, gcb+(size_t)t*128, rep);
    // z = relu([h, rep, phi] @ fuse_W + fuse_b)  -> straight into d_out
    gemm_k<false><<<dim3(GB,1),256,0,stream>>>(
      ASegs{hin,rep,phi,256,128,256}, fuseW, fuseb, nullptr,
      zt, NN,640,128,128,1);
    // gi = [z,c,yh] @ Wih^T + bih ; gh = h @ Whh^T + bhh
    gemm_k<true ><<<dim3(GB,6),256,0,stream>>>(
      ASegs{zt, Cc+(size_t)t*NN*8, Yh+(size_t)t*NN*16,128,8,16}, Wih, bih, nullptr,
      gi, NN,152,768,768,0);
    gemm_k<true ><<<dim3(GB,6),256,0,stream>>>(
      ASegs{hin,nullptr,nullptr,256,0,0}, Whh, bhh, nullptr,
      gh, NN,256,768,768,0);
    gru_k<<<NN,256,0,stream>>>(gi,gh,hin,hout);
    // heads: u2 = relu(z @ [o00_W|o10_W] + [b]) ; y0=u2[:,:128]@o01, y1=u2[:,128:]@o11
    gemm_k<false><<<dim3(GB,2),256,0,stream>>>(
      ASegs{zt,nullptr,nullptr,128,0,0}, woc, b2, nullptr,
      u2, NN,128,256,256,1);
    heads_dot_k<<<NN/4,256,0,stream>>>(u2, o01W,o01b, o11W,o11b,
      out + TN + (size_t)t*NN,   // y0 (second output block)
      out + (size_t)t*NN);       // y1 (first output block)
    // propensity: s = sigmoid((z@ps1_W)*bn_scale + (ps1_b*bn_scale + bn_b))
    gemm_k<false><<<dim3(GB,1),256,0,stream>>>(
      ASegs{zt,nullptr,nullptr,128,0,0}, ps1W, psb, psc,
      sbuf, NN,128,100,100,2);
    ps2_k<<<NN/4,256,0,stream>>>(sbuf, ps2W, ps2b, out+psoff+(size_t)t*NN*2);
  }
  (void)in_sizes; (void)n_in; (void)out_size; (void)ws_size;
}

// Round 2
// 4782.739 us; speedup vs baseline: 3.6423x; 3.6423x over previous
//
#include <hip/hip_runtime.h>
#include <math.h>

#define T_STEPS 8
#define NN 50000
#define EE 800000
#define TN (T_STEPS*NN)   // 400000
#define TE (T_STEPS*EE)   // 6400000

typedef unsigned int uint;
typedef unsigned short ushort;
typedef __attribute__((ext_vector_type(8))) short short8;
typedef __attribute__((ext_vector_type(4))) float f32x4;

__device__ __forceinline__ float sigf(float x){ return 1.0f/(1.0f+expf(-x)); }
__device__ __forceinline__ ushort f2b(float f){
  uint x = __float_as_uint(f);
  uint r = (x + 0x7fffu + ((x>>16)&1u)) >> 16;
  return (ushort)r;
}
__device__ __forceinline__ float b2f(ushort u){ return __uint_as_float(((uint)u)<<16); }

__device__ __forceinline__ float wred64(float v){
#pragma unroll
  for(int o=32;o>0;o>>=1) v += __shfl_xor(v, o);
  return v;
}

__device__ __forceinline__ void gload16(const ushort* g, ushort* l){
  __builtin_amdgcn_global_load_lds(
      (const __attribute__((address_space(1))) void*)g,
      (__attribute__((address_space(3))) void*)l, 16, 0, 0);
}

// ================= bf16 MFMA GEMM =================
// C[M,NO] = act( (A[M,K2] @ W[NO,K2]^T) * scale + bias )
// A: bf16 row-major ld=ldA ; W: bf16 [NOpad][K2] row-major (B^T layout)
// 128x128 tile, BK=64, 4 waves, each wave 64x64 (4x4 frags of 16x16x32)
__global__ __launch_bounds__(256,2) void gemm_bf(
    const ushort* __restrict__ A, int ldA,
    const ushort* __restrict__ W, int K2,
    const float* __restrict__ bias, const float* __restrict__ scale, int act,
    float* __restrict__ C32, int ldc,
    ushort* __restrict__ C16, int ldb,
    int Nrow, int NOvalid)
{
  __shared__ __align__(16) ushort As[8192];   // [128 rows][64 bf16] swizzled
  __shared__ __align__(16) ushort Bs[8192];
  const int tid  = threadIdx.x;
  const int lane = tid & 63;
  const int wid  = __builtin_amdgcn_readfirstlane(tid >> 6);
  const int brow = blockIdx.x*128;
  const int bcol = blockIdx.y*128;
  const int wr = wid>>1, wc = wid&1;

  f32x4 acc[4][4];
#pragma unroll
  for(int m=0;m<4;m++)
#pragma unroll
    for(int n=0;n<4;n++) acc[m][n] = (f32x4){0.f,0.f,0.f,0.f};

  const int nk = K2 >> 6;
  for (int kt=0; kt<nk; ++kt){
#pragma unroll
    for (int i=0;i<4;i++){            // stage A (16KB), pre-swizzled source
      int lin = wid*256 + i*64 + lane;          // 16B-unit index
      int row = lin>>3, s = lin&7;
      int grow = brow + row; if (grow >= Nrow) grow = Nrow-1;
      const ushort* gp = A + (size_t)grow*ldA + kt*64 + ((s ^ (row&7))<<3);
      gload16(gp, As + (size_t)(wid*256 + i*64)*8);
    }
#pragma unroll
    for (int i=0;i<4;i++){            // stage B
      int lin = wid*256 + i*64 + lane;
      int row = lin>>3, s = lin&7;
      const ushort* gp = W + (size_t)(bcol+row)*K2 + kt*64 + ((s ^ (row&7))<<3);
      gload16(gp, Bs + (size_t)(wid*256 + i*64)*8);
    }
    __syncthreads();
#pragma unroll
    for (int kk=0;kk<2;kk++){
      short8 a[4], b[4];
#pragma unroll
      for (int m=0;m<4;m++){
        int R = wr*64 + m*16 + (lane&15);
        int slot = (kk*4 + (lane>>4)) ^ (R&7);
        a[m] = *(const short8*)&As[R*64 + slot*8];
      }
#pragma unroll
      for (int n=0;n<4;n++){
        int R = wc*64 + n*16 + (lane&15);
        int slot = (kk*4 + (lane>>4)) ^ (R&7);
        b[n] = *(const short8*)&Bs[R*64 + slot*8];
      }
#pragma unroll
      for (int m=0;m<4;m++)
#pragma unroll
        for (int n=0;n<4;n++)
          acc[m][n] = __builtin_amdgcn_mfma_f32_16x16x32_bf16(a[m], b[n], acc[m][n], 0,0,0);
    }
    __syncthreads();
  }
  // epilogue: C/D layout col=lane&15, row=(lane>>4)*4+q
  const int rbase = brow + wr*64 + (lane>>4)*4;
  const int cbase = bcol + wc*64 + (lane&15);
#pragma unroll
  for (int m=0;m<4;m++){
#pragma unroll
    for (int q=0;q<4;q++){
      int r = rbase + m*16 + q;
      if (r >= Nrow) continue;
#pragma unroll
      for (int n=0;n<4;n++){
        int c = cbase + n*16;
        if (c >= NOvalid) continue;
        float v = acc[m][n][q];
        if (scale) v *= scale[c];
        if (bias)  v += bias[c];
        if (act==1) v = fmaxf(v, 0.f);
        else if (act==2) v = sigf(v);
        if (C32) C32[(size_t)r*ldc + c] = v;
        if (C16) C16[(size_t)r*ldb + c] = f2b(v);
      }
    }
  }
}

// ================= CSR build (unchanged from round 1) =================
__global__ void count_k(const int* __restrict__ ei, const float* __restrict__ ewl,
                        int* __restrict__ cnt, float* __restrict__ degw)
{
  int idx = blockIdx.x*256 + threadIdx.x;
  if (idx >= TE) return;
  int t = idx / EE;
  int e = idx - t*EE;
  const int* dst = ei + (size_t)t*2*EE + EE;
  int d = dst[e];
  atomicAdd(&cnt[t*NN + d], 1);
  atomicAdd(&degw[t*NN + d], sigf(ewl[idx]));
}

__global__ void scan1_k(const int* __restrict__ in, int* __restrict__ outv,
                        int* __restrict__ partials, int n)
{
  __shared__ int sh[256];
  int base = blockIdx.x*1024;
  int tid = threadIdx.x;
  int v[4]; int s=0;
#pragma unroll
  for (int i=0;i<4;i++){ int idx=base+tid*4+i; v[i] = (idx<n)? in[idx]:0; s+=v[i]; }
  sh[tid]=s; __syncthreads();
  for (int o=1;o<256;o<<=1){
    int t2 = (tid>=o)? sh[tid-o]:0;
    __syncthreads();
    sh[tid]+=t2;
    __syncthreads();
  }
  int excl = sh[tid]-s;
#pragma unroll
  for (int i=0;i<4;i++){ int idx=base+tid*4+i; if(idx<n) outv[idx]=excl; excl+=v[i]; }
  if (tid==255) partials[blockIdx.x]=sh[255];
}

__global__ void scan2_k(int* p, int np){
  __shared__ int sh[256];
  __shared__ int run;
  int tid=threadIdx.x;
  if(tid==0) run=0;
  __syncthreads();
  for(int base=0;base<np;base+=256){
    int v = (base+tid<np)? p[base+tid]:0;
    sh[tid]=v; __syncthreads();
    for(int o=1;o<256;o<<=1){
      int t2 = (tid>=o)? sh[tid-o]:0;
      __syncthreads();
      sh[tid]+=t2;
      __syncthreads();
    }
    int incl=sh[tid];
    int r0=run;
    __syncthreads();
    if(base+tid<np) p[base+tid]=r0+incl-v;
    __syncthreads();
    if(tid==0) run = r0 + sh[255];
    __syncthreads();
  }
}

__global__ void scan3_k(int* __restrict__ offs, const int* __restrict__ parts,
                        int* __restrict__ cur, int n){
  int idx = blockIdx.x*256+threadIdx.x;
  if (idx==0) offs[n] = TE;
  if (idx<n){ int v = offs[idx] + parts[idx>>10]; offs[idx]=v; cur[idx]=v; }
}

__global__ void dinv_k(const float* __restrict__ degw, float* __restrict__ dnv,
                       float* __restrict__ invd){
  int idx = blockIdx.x*256+threadIdx.x;
  if (idx>=TN) return;
  float dv = degw[idx]+1.f;
  dnv[idx]  = rsqrtf(dv);
  invd[idx] = 1.f/dv;
}

__global__ void fill_k(const int* __restrict__ ei, const float* __restrict__ ewl,
                       const float* __restrict__ dnv, int* __restrict__ cur,
                       int* __restrict__ esrc, float* __restrict__ enorm)
{
  int idx = blockIdx.x*256 + threadIdx.x;
  if (idx >= TE) return;
  int t = idx / EE;
  int e = idx - t*EE;
  const int* srcp = ei + (size_t)t*2*EE;
  const int* dstp = srcp + EE;
  int s=srcp[e], d=dstp[e];
  float nr = dnv[t*NN+s] * sigf(ewl[idx]) * dnv[t*NN+d];
  int pos = atomicAdd(&cur[t*NN+d], 1);
  esrc[pos]=s; enorm[pos]=nr;
}

// ================= GCN gather (bf16 xw -> bf16 rep into hrp) =================
__global__ __launch_bounds__(256) void gather_k(const int* __restrict__ offs_t,
    const int* __restrict__ esrc, const float* __restrict__ enorm,
    const ushort* __restrict__ xwb, const float* __restrict__ invd_t,
    const float* __restrict__ gcb_t, ushort* __restrict__ hrp)
{
  int node = blockIdx.x*4 + (threadIdx.x>>6);
  int lane = threadIdx.x & 63;
  if (node >= NN) return;
  int o0 = offs_t[node], o1 = offs_t[node+1];
  float a0=0.f, a1=0.f;
  for (int j=o0;j<o1;++j){
    int s = esrc[j];
    float nr = enorm[j];
    uint u = ((const uint*)(xwb + (size_t)s*128))[lane];
    a0 = fmaf(nr, b2f((ushort)(u&0xffff)), a0);
    a1 = fmaf(nr, b2f((ushort)(u>>16)),   a1);
  }
  float sl = invd_t[node];
  uint us = ((const uint*)(xwb + (size_t)node*128))[lane];
  a0 = fmaf(sl, b2f((ushort)(us&0xffff)), a0) + gcb_t[2*lane];
  a1 = fmaf(sl, b2f((ushort)(us>>16)),   a1) + gcb_t[2*lane+1];
  a0 = fmaxf(a0, 0.f); a1 = fmaxf(a1, 0.f);
  uint pk = (uint)f2b(a0) | ((uint)f2b(a1) << 16);
  ((uint*)(hrp + (size_t)node*640 + 256))[lane] = pk;
}

// ================= GRU pointwise =================
__global__ void gru_k(const float* __restrict__ gi, const float* __restrict__ gh,
                      const float* __restrict__ h, float* __restrict__ hout,
                      ushort* __restrict__ hrp)
{
  int node = blockIdx.x; int j = threadIdx.x;
  size_t b=(size_t)node*768;
  float r  = sigf(gi[b+j]     + gh[b+j]);
  float u  = sigf(gi[b+256+j] + gh[b+256+j]);
  float nn = tanhf(gi[b+512+j] + r*gh[b+512+j]);
  float v = (1.f-u)*nn + u*h[(size_t)node*256+j];
  hout[(size_t)node*256+j] = v;
  hrp[(size_t)node*640 + j] = f2b(v);
}

// ================= heads =================
__global__ __launch_bounds__(256) void heads_dot_k(const float* __restrict__ u2,
    const float* __restrict__ w01, const float* __restrict__ b01,
    const float* __restrict__ w11, const float* __restrict__ b11,
    float* __restrict__ y0out, float* __restrict__ y1out)
{
  int node = blockIdx.x*4 + (threadIdx.x>>6);
  int lane = threadIdx.x&63;
  if (node>=NN) return;
  const float* row = u2 + (size_t)node*256;
  float a0 = row[lane]*w01[lane]     + row[64+lane]*w01[64+lane];
  float a1 = row[128+lane]*w11[lane] + row[192+lane]*w11[64+lane];
  a0 = wred64(a0); a1 = wred64(a1);
  if (lane==0){ y0out[node]=a0+b01[0]; y1out[node]=a1+b11[0]; }
}

__global__ __launch_bounds__(256) void ps2_k(const float* __restrict__ sbuf,
    const float* __restrict__ W2, const float* __restrict__ b2,
    float* __restrict__ psout)
{
  int node = blockIdx.x*4+(threadIdx.x>>6);
  int lane=threadIdx.x&63;
  if(node>=NN) return;
  const float* srow = sbuf + (size_t)node*100;
  float a0=0.f,a1=0.f;
  for (int f=lane; f<100; f+=64){
    float sv=srow[f];
    a0 += sv*W2[2*f]; a1 += sv*W2[2*f+1];
  }
  a0=wred64(a0); a1=wred64(a1);
  if(lane==0){
    float l0=a0+b2[0], l1=a1+b2[1];
    float m=fmaxf(l0,l1);
    float e0=expf(l0-m), e1=expf(l1-m);
    float inv=1.f/(e0+e1);
    psout[(size_t)node*2]   = e0*inv;
    psout[(size_t)node*2+1] = e1*inv;
  }
}

// ================= weight/activation prep =================
// dst[o][k] = src[k][o]  (pad k>=K and o>=Osrc with 0) ; per blockIdx.y batch
__global__ void convT_k(ushort* __restrict__ dst, const float* __restrict__ src,
                        int O, int Osrc, int K, int Kp)
{
  int idx = blockIdx.x*256 + threadIdx.x;
  if (idx >= O*Kp) return;
  dst += (size_t)blockIdx.y * O * Kp;
  src += (size_t)blockIdx.y * K * Osrc;
  int o = idx / Kp, k = idx - o*Kp;
  float v = (k<K && o<Osrc) ? src[(size_t)k*Osrc + o] : 0.f;
  dst[idx] = f2b(v);
}

// dst[o][k] = src[o][k] (pad k>=K with 0)
__global__ void convN_k(ushort* __restrict__ dst, const float* __restrict__ src,
                        int O, int K, int Kp)
{
  int idx = blockIdx.x*256 + threadIdx.x;
  if (idx >= O*Kp) return;
  int o = idx / Kp, k = idx - o*Kp;
  dst[idx] = f2b((k<K) ? src[(size_t)o*K + k] : 0.f);
}

__global__ void woc_k(ushort* __restrict__ dst, const float* __restrict__ o00W,
                      const float* __restrict__ o10W)
{
  int idx = blockIdx.x*256 + threadIdx.x;
  if (idx >= 256*128) return;
  int o = idx >> 7, k = idx & 127;
  float v = (o<128) ? o00W[(size_t)k*128 + o] : o10W[(size_t)k*128 + (o-128)];
  dst[idx] = f2b(v);
}

__global__ void misc_k(const float* __restrict__ o00b, const float* __restrict__ o10b,
                       const float* __restrict__ ps1b, const float* __restrict__ bng,
                       const float* __restrict__ bnb,
                       float* __restrict__ b2, float* __restrict__ psc, float* __restrict__ psb)
{
  int i = threadIdx.x;
  if (i<256) b2[i] = (i<128)? o00b[i] : o10b[i-128];
  if (i<100){ float sc = bng[i]*rsqrtf(1.f+1e-5f); psc[i]=sc; psb[i]=ps1b[i]*sc+bnb[i]; }
}

__global__ void xconv_k(ushort* __restrict__ dst, const float* __restrict__ src, long n4)
{
  long i = (long)blockIdx.x*256 + threadIdx.x;
  if (i >= n4) return;
  float4 v = ((const float4*)src)[i];
  uint lo = (uint)f2b(v.x) | ((uint)f2b(v.y)<<16);
  uint hi = (uint)f2b(v.z) | ((uint)f2b(v.w)<<16);
  ((uint2*)dst)[i] = make_uint2(lo, hi);
}

// fill zcyh cols 128..191 for step t : c(8) | yh(16) | zeros(40)
__global__ void cyh_k(ushort* __restrict__ zcyh, const float* __restrict__ Cc,
                      const float* __restrict__ Yh)
{
  int gid = blockIdx.x*256 + threadIdx.x;   // NN*64
  int n = gid >> 6, l = gid & 63;
  if (n >= NN) return;
  float v = 0.f;
  if (l < 8)       v = Cc[(size_t)n*8 + l];
  else if (l < 24) v = Yh[(size_t)n*16 + (l-8)];
  zcyh[(size_t)n*192 + 128 + l] = f2b(v);
}

extern "C" void kernel_launch(void* const* d_in, const int* in_sizes, int n_in,
                              void* d_out_v, int out_size, void* d_ws, size_t ws_size,
                              hipStream_t stream)
{
  const float* X    = (const float*)d_in[0];
  const float* Cc   = (const float*)d_in[1];
  const float* Yh   = (const float*)d_in[2];
  const int*   EI   = (const int*)  d_in[3];
  const float* phiW = (const float*)d_in[4];  const float* phib = (const float*)d_in[5];
  const float* gcW  = (const float*)d_in[6];  const float* gcb  = (const float*)d_in[7];
  const float* ewl  = (const float*)d_in[8];
  const float* fuseW= (const float*)d_in[9];  const float* fuseb= (const float*)d_in[10];
  const float* o00W = (const float*)d_in[11]; const float* o00b = (const float*)d_in[12];
  const float* o10W = (const float*)d_in[13]; const float* o10b = (const float*)d_in[14];
  const float* o01W = (const float*)d_in[15]; const float* o01b = (const float*)d_in[16];
  const float* o11W = (const float*)d_in[17]; const float* o11b = (const float*)d_in[18];
  const float* ps1W = (const float*)d_in[19]; const float* ps1b = (const float*)d_in[20];
  const float* bng  = (const float*)d_in[21]; const float* bnb  = (const float*)d_in[22];
  const float* ps2W = (const float*)d_in[23]; const float* ps2b = (const float*)d_in[24];
  const float* Wih  = (const float*)d_in[25]; const float* Whh  = (const float*)d_in[26];
  const float* bih  = (const float*)d_in[27]; const float* bhh  = (const float*)d_in[28];
  float* out = (float*)d_out_v;

  char* wsb = (char*)d_ws;
  size_t off=0;
  auto alloc=[&](size_t bytes)->void*{
    void* p = wsb + off;
    off = (off + bytes + 255) & ~(size_t)255;
    return p;
  };
  int*   cnt   = (int*)  alloc((size_t)TN*4);
  int*   cur   = (int*)  alloc((size_t)TN*4);
  int*   offs  = (int*)  alloc(((size_t)TN+1)*4);
  float* degw  = (float*)alloc((size_t)TN*4);
  float* dnv   = (float*)alloc((size_t)TN*4);
  float* invd  = (float*)alloc((size_t)TN*4);
  int*   esrc  = (int*)  alloc((size_t)TE*4);
  float* enorm = (float*)alloc((size_t)TE*4);
  int*   parts = (int*)  alloc(4096);
  ushort* Xb   = (ushort*)alloc((size_t)T_STEPS*NN*128*2);
  ushort* hrp  = (ushort*)alloc((size_t)NN*640*2);   // [h(256) | rep(128) | phi(256)]
  ushort* zcyh = (ushort*)alloc((size_t)NN*192*2);   // [z(128) | c(8) | yh(16) | pad(40)]
  ushort* xwb  = (ushort*)alloc((size_t)NN*128*2);
  float* hb0   = (float*)alloc((size_t)NN*256*4);
  float* hb1   = (float*)alloc((size_t)NN*256*4);
  float* gi    = (float*)alloc((size_t)NN*768*4);
  float* gh    = (float*)alloc((size_t)NN*768*4);
  ushort* phiWt= (ushort*)alloc(256*128*2);
  ushort* gcWt = (ushort*)alloc((size_t)T_STEPS*128*256*2);
  ushort* fuseWt=(ushort*)alloc(128*640*2);
  ushort* WihT = (ushort*)alloc(768*192*2);
  ushort* WhhB = (ushort*)alloc(768*256*2);
  ushort* wocT = (ushort*)alloc(256*128*2);
  ushort* ps1T = (ushort*)alloc(128*128*2);
  float* b2    = (float*)alloc(256*4);
  float* psc   = (float*)alloc(128*4);
  float* psb   = (float*)alloc(128*4);
  float* u2    = gi;   // reused after gru consumes gi/gh
  float* sbuf  = gh;

  hipMemsetAsync(cnt,  0, (size_t)TN*4, stream);
  hipMemsetAsync(degw, 0, (size_t)TN*4, stream);
  hipMemsetAsync(hb0,  0, (size_t)NN*256*4, stream);
  hipMemsetAsync(hrp,  0, (size_t)NN*640*2, stream);

  // --- prep ---
  misc_k<<<1,256,0,stream>>>(o00b,o10b,ps1b,bng,bnb,b2,psc,psb);
  convT_k<<<dim3((256*128+255)/256,1),256,0,stream>>>(phiWt, phiW, 256,256,128,128);
  convT_k<<<dim3((128*256+255)/256,T_STEPS),256,0,stream>>>(gcWt, gcW, 128,128,256,256);
  convT_k<<<dim3((128*640+255)/256,1),256,0,stream>>>(fuseWt, fuseW, 128,128,640,640);
  convT_k<<<dim3((128*128+255)/256,1),256,0,stream>>>(ps1T, ps1W, 128,100,128,128);
  convN_k<<<(768*192+255)/256,256,0,stream>>>(WihT, Wih, 768,152,192);
  convN_k<<<(768*256+255)/256,256,0,stream>>>(WhhB, Whh, 768,256,256);
  woc_k<<<(256*128+255)/256,256,0,stream>>>(wocT, o00W, o10W);
  xconv_k<<<(int)(((size_t)T_STEPS*NN*128/4+255)/256),256,0,stream>>>(Xb, X, (long)T_STEPS*NN*128/4);

  // --- CSR build ---
  count_k<<<(TE+255)/256,256,0,stream>>>(EI,ewl,cnt,degw);
  scan1_k<<<(TN+1023)/1024,256,0,stream>>>(cnt,offs,parts,TN);
  scan2_k<<<1,256,0,stream>>>(parts,(TN+1023)/1024);
  scan3_k<<<(TN+255)/256,256,0,stream>>>(offs,parts,cur,TN);
  dinv_k<<<(TN+255)/256,256,0,stream>>>(degw,dnv,invd);
  fill_k<<<(TE+255)/256,256,0,stream>>>(EI,ewl,dnv,cur,esrc,enorm);

  const size_t zoff  = (size_t)2*TN;               // y1,y0 regions first
  const size_t psoff = zoff + (size_t)TN*128;
  const size_t hoff  = psoff + (size_t)TN*2;
  constexpr int GX = (NN+127)/128;                 // 391

  for (int t=0;t<T_STEPS;t++){
    const float* hin = (t&1)? hb1: hb0;
    float* hout = (t==T_STEPS-1)? (out+hoff) : ((t&1)? hb0: hb1);
    float* zt = out + zoff + (size_t)t*NN*128;

    cyh_k<<<(NN*64+255)/256,256,0,stream>>>(zcyh, Cc+(size_t)t*NN*8, Yh+(size_t)t*NN*16);

    // phi = relu(X_t @ phi_W + phi_b)           -> bf16 into hrp[:,384:640]
    gemm_bf<<<dim3(GX,2),256,0,stream>>>(Xb+(size_t)t*NN*128,128, phiWt,128,
      phib,nullptr,1, nullptr,0, hrp+384,640, NN,256);
    // xw = phi @ gc_W[t]                        -> bf16 xwb
    gemm_bf<<<dim3(GX,1),256,0,stream>>>(hrp+384,640, gcWt+(size_t)t*128*256,256,
      nullptr,nullptr,0, nullptr,0, xwb,128, NN,128);
    // rep = relu(agg + xw/deg + gc_b[t])        -> bf16 into hrp[:,256:384]
    gather_k<<<NN/4,256,0,stream>>>(offs+(size_t)t*NN, esrc, enorm, xwb,
                                    invd+(size_t)t*NN, gcb+(size_t)t*128, hrp);
    // z = relu([h,rep,phi] @ fuse_W + fuse_b)   -> fp32 out(zt) + bf16 zcyh[:,0:128]
    gemm_bf<<<dim3(GX,1),256,0,stream>>>(hrp,640, fuseWt,640,
      fuseb,nullptr,1, zt,128, zcyh,192, NN,128);
    // gi = [z,c,yh] @ Wih^T + bih
    gemm_bf<<<dim3(GX,6),256,0,stream>>>(zcyh,192, WihT,192,
      bih,nullptr,0, gi,768, nullptr,0, NN,768);
    // gh = h @ Whh^T + bhh
    gemm_bf<<<dim3(GX,6),256,0,stream>>>(hrp,640, WhhB,256,
      bhh,nullptr,0, gh,768, nullptr,0, NN,768);
    gru_k<<<NN,256,0,stream>>>(gi,gh,hin,hout,hrp);
    // heads: u2 = relu(z @ [o00|o10] + b)
    gemm_bf<<<dim3(GX,2),256,0,stream>>>(zcyh,192, wocT,128,
      b2,nullptr,1, u2,256, nullptr,0, NN,256);
    heads_dot_k<<<NN/4,256,0,stream>>>(u2, o01W,o01b, o11W,o11b,
      out + TN + (size_t)t*NN,   // y0
      out + (size_t)t*NN);       // y1
    // propensity: s = sigmoid((z@ps1_W)*bn_scale + fused_bias)
    gemm_bf<<<dim3(GX,1),256,0,stream>>>(zcyh,192, ps1T,128,
      psb,psc,2, sbuf,100, nullptr,0, NN,100);
    ps2_k<<<NN/4,256,0,stream>>>(sbuf, ps2W, ps2b, out+psoff+(size_t)t*NN*2);
  }
  (void)in_sizes; (void)n_in; (void)out_size; (void)ws_size;
}

// Round 3
// 2838.438 us; speedup vs baseline: 6.1372x; 1.6850x over previous
//
#include <hip/hip_runtime.h>
#include <math.h>

#define T_STEPS 8
#define NN 50000
#define EE 800000
#define TN (T_STEPS*NN)   // 400000
#define TE (T_STEPS*EE)   // 6400000

typedef unsigned int uint;
typedef unsigned short ushort;
typedef unsigned long long u64;
typedef __attribute__((ext_vector_type(8))) short short8;
typedef __attribute__((ext_vector_type(4))) float f32x4;

__device__ __forceinline__ float sigf(float x){ return 1.0f/(1.0f+expf(-x)); }
__device__ __forceinline__ ushort f2b(float f){
  uint x = __float_as_uint(f);
  uint r = (x + 0x7fffu + ((x>>16)&1u)) >> 16;
  return (ushort)r;
}
__device__ __forceinline__ float b2f(ushort u){ return __uint_as_float(((uint)u)<<16); }

__device__ __forceinline__ void gload16(const ushort* g, ushort* l){
  __builtin_amdgcn_global_load_lds(
      (const __attribute__((address_space(1))) void*)g,
      (__attribute__((address_space(3))) void*)l, 16, 0, 0);
}

// stage ROWS x 64 bf16 tile into LDS (pre-swizzled source, linear dest)
template<int ROWS>
__device__ __forceinline__ void stage_tile(const ushort* base, int ld, int rowclamp,
                                           ushort* lds, int lane, int wid){
  constexpr int ITERS = ROWS/32;
#pragma unroll
  for (int i=0;i<ITERS;i++){
    int lin = i*256 + wid*64 + lane;
    int row = lin>>3, s = lin&7;
    int gr = row; if (gr > rowclamp) gr = rowclamp;
    const ushort* gp = base + (size_t)gr*ld + ((s ^ (row&7))<<3);
    gload16(gp, lds + (size_t)(i*256 + wid*64)*8);
  }
}

__device__ __forceinline__ short8 fragld(const ushort* lds, int R, int kk, int lane){
  int slot = (kk*4 + (lane>>4)) ^ (R&7);
  return *(const short8*)&lds[R*64 + slot*8];
}

// ================= generic bf16 MFMA GEMM (128x128 tile, 2-seg A) =================
__global__ __launch_bounds__(256,2) void gemm_bf(
    const ushort* __restrict__ A0, int ld0, int w0,
    const ushort* __restrict__ A1, int ld1,
    const ushort* __restrict__ W, int K2,
    const float* __restrict__ bias, int act,
    float* __restrict__ C32, int ldc,
    ushort* __restrict__ C16, int ldb,
    int Nrow, int NOvalid)
{
  __shared__ __align__(16) ushort As[8192];
  __shared__ __align__(16) ushort Bs[8192];
  const int tid  = threadIdx.x;
  const int lane = tid & 63;
  const int wid  = __builtin_amdgcn_readfirstlane(tid >> 6);
  const int brow = blockIdx.x*128;
  const int bcol = blockIdx.y*128;
  const int wr = wid>>1, wc = wid&1;

  f32x4 acc[4][4];
#pragma unroll
  for(int m=0;m<4;m++)
#pragma unroll
    for(int n=0;n<4;n++) acc[m][n] = (f32x4){0.f,0.f,0.f,0.f};

  const int nk = K2 >> 6;
  for (int kt=0; kt<nk; ++kt){
    int col0 = kt*64;
    const ushort* ab; int ald;
    if (col0 < w0){ ab = A0 + col0; ald = ld0; }
    else          { ab = A1 + (col0 - w0); ald = ld1; }
    stage_tile<128>(ab + (size_t)brow*ald, ald, Nrow-1-brow, As, lane, wid);
    stage_tile<128>(W + (size_t)bcol*K2 + col0, K2, 1<<30, Bs, lane, wid);
    __syncthreads();
#pragma unroll
    for (int kk=0;kk<2;kk++){
      short8 a[4], b[4];
#pragma unroll
      for (int m=0;m<4;m++) a[m] = fragld(As, wr*64 + m*16 + (lane&15), kk, lane);
#pragma unroll
      for (int n=0;n<4;n++) b[n] = fragld(Bs, wc*64 + n*16 + (lane&15), kk, lane);
#pragma unroll
      for (int m=0;m<4;m++)
#pragma unroll
        for (int n=0;n<4;n++)
          acc[m][n] = __builtin_amdgcn_mfma_f32_16x16x32_bf16(a[m], b[n], acc[m][n], 0,0,0);
    }
    __syncthreads();
  }
  const int rbase = brow + wr*64 + (lane>>4)*4;
  const int cbase = bcol + wc*64 + (lane&15);
#pragma unroll
  for (int m=0;m<4;m++){
#pragma unroll
    for (int q=0;q<4;q++){
      int r = rbase + m*16 + q;
      if (r >= Nrow) continue;
#pragma unroll
      for (int n=0;n<4;n++){
        int c = cbase + n*16;
        if (c >= NOvalid) continue;
        float v = acc[m][n][q];
        if (bias)  v += bias[c];
        if (act==1) v = fmaxf(v, 0.f);
        if (C32) C32[(size_t)r*ldc + c] = v;
        if (C16) C16[(size_t)r*ldb + c] = f2b(v);
      }
    }
  }
}

// ================= fused GRU GEMM: [zcyh | h] @ Wgru^T -> gates -> h_new =========
// NO=1024, cols c = G*64 + gate*16 + jj  (j = G*16+jj)
__global__ __launch_bounds__(256,2) void gemm_gru(
    const ushort* __restrict__ A0, int ld0, int w0,      // zcyh, 192
    const ushort* __restrict__ A1, int ld1,              // hbf_in, 256
    const ushort* __restrict__ W,                        // Wgru [1024][448]
    const float* __restrict__ bg,                        // [1024]
    const float* __restrict__ hin,                       // fp32 h_t
    float* __restrict__ hout, ushort* __restrict__ hbfo,
    int Nrow)
{
  __shared__ __align__(16) ushort As[8192];
  __shared__ __align__(16) ushort Bs[8192];
  const int tid  = threadIdx.x;
  const int lane = tid & 63;
  const int wid  = __builtin_amdgcn_readfirstlane(tid >> 6);
  const int brow = blockIdx.x*128;
  const int bcol = blockIdx.y*128;
  const int wr = wid>>1, wc = wid&1;
  const int K2 = 448;

  f32x4 acc[4][4];
#pragma unroll
  for(int m=0;m<4;m++)
#pragma unroll
    for(int n=0;n<4;n++) acc[m][n] = (f32x4){0.f,0.f,0.f,0.f};

  for (int kt=0; kt<7; ++kt){
    int col0 = kt*64;
    const ushort* ab; int ald;
    if (col0 < w0){ ab = A0 + col0; ald = ld0; }
    else          { ab = A1 + (col0 - w0); ald = ld1; }
    stage_tile<128>(ab + (size_t)brow*ald, ald, Nrow-1-brow, As, lane, wid);
    stage_tile<128>(W + (size_t)bcol*K2 + col0, K2, 1<<30, Bs, lane, wid);
    __syncthreads();
#pragma unroll
    for (int kk=0;kk<2;kk++){
      short8 a[4], b[4];
#pragma unroll
      for (int m=0;m<4;m++) a[m] = fragld(As, wr*64 + m*16 + (lane&15), kk, lane);
#pragma unroll
      for (int n=0;n<4;n++) b[n] = fragld(Bs, wc*64 + n*16 + (lane&15), kk, lane);
#pragma unroll
      for (int m=0;m<4;m++)
#pragma unroll
        for (int n=0;n<4;n++)
          acc[m][n] = __builtin_amdgcn_mfma_f32_16x16x32_bf16(a[m], b[n], acc[m][n], 0,0,0);
    }
    __syncthreads();
  }
  const int jj = lane&15;
  const int j  = blockIdx.y*32 + wc*16 + jj;       // hidden unit index
  const int rbase = brow + wr*64 + (lane>>4)*4;
  float bb[4];
#pragma unroll
  for (int n=0;n<4;n++) bb[n] = bg[bcol + wc*64 + n*16 + jj];
#pragma unroll
  for (int m=0;m<4;m++){
#pragma unroll
    for (int q=0;q<4;q++){
      int r = rbase + m*16 + q;
      if (r >= Nrow) continue;
      float v0 = acc[m][0][q] + bb[0];
      float v1 = acc[m][1][q] + bb[1];
      float v2 = acc[m][2][q] + bb[2];
      float v3 = acc[m][3][q] + bb[3];
      float rg = sigf(v0), ug = sigf(v1);
      float ng = tanhf(v2 + rg*v3);
      float ho = hin[(size_t)r*256 + j];
      float hn = (1.f-ug)*ng + ug*ho;
      hout[(size_t)r*256 + j] = hn;
      hbfo[(size_t)r*256 + j] = f2b(hn);
    }
  }
}

// ================= fused outcome heads: relu(z@woc + b) @ {o01,o11} ==============
// tile 64 rows x 256 cols, 4 waves in col dim
__global__ __launch_bounds__(256,2) void heads_k(
    const ushort* __restrict__ A, int ldA,               // zcyh
    const ushort* __restrict__ W,                        // wocT [256][128]
    const float* __restrict__ o00b, const float* __restrict__ o10b,
    const float* __restrict__ w01, const float* __restrict__ b01,
    const float* __restrict__ w11, const float* __restrict__ b11,
    float* __restrict__ y0out, float* __restrict__ y1out, int Nrow)
{
  __shared__ __align__(16) ushort As[4096];
  __shared__ __align__(16) ushort Bs[16384];
  __shared__ float shy[4][64];
  const int tid  = threadIdx.x;
  const int lane = tid & 63;
  const int wid  = __builtin_amdgcn_readfirstlane(tid >> 6);
  const int brow = blockIdx.x*64;

  f32x4 acc[4][4];
#pragma unroll
  for(int m=0;m<4;m++)
#pragma unroll
    for(int n=0;n<4;n++) acc[m][n] = (f32x4){0.f,0.f,0.f,0.f};

  for (int kt=0; kt<2; ++kt){
    stage_tile<64>(A + (size_t)brow*ldA + kt*64, ldA, Nrow-1-brow, As, lane, wid);
    stage_tile<256>(W + kt*64, 128, 1<<30, Bs, lane, wid);
    __syncthreads();
#pragma unroll
    for (int kk=0;kk<2;kk++){
      short8 a[4], b[4];
#pragma unroll
      for (int m=0;m<4;m++) a[m] = fragld(As, m*16 + (lane&15), kk, lane);
#pragma unroll
      for (int n=0;n<4;n++) b[n] = fragld(Bs, wid*64 + n*16 + (lane&15), kk, lane);
#pragma unroll
      for (int m=0;m<4;m++)
#pragma unroll
        for (int n=0;n<4;n++)
          acc[m][n] = __builtin_amdgcn_mfma_f32_16x16x32_bf16(a[m], b[n], acc[m][n], 0,0,0);
    }
    __syncthreads();
  }
  float bb[4], ww[4];
#pragma unroll
  for (int n=0;n<4;n++){
    int c = wid*64 + n*16 + (lane&15);
    bb[n] = (c<128)? o00b[c] : o10b[c-128];
    ww[n] = (c<128)? w01[c]  : w11[c-128];
  }
#pragma unroll
  for (int m=0;m<4;m++){
#pragma unroll
    for (int q=0;q<4;q++){
      float p = 0.f;
#pragma unroll
      for (int n=0;n<4;n++) p += fmaxf(acc[m][n][q] + bb[n], 0.f) * ww[n];
#pragma unroll
      for (int o=1;o<16;o<<=1) p += __shfl_xor(p, o);
      if ((lane&15)==0) shy[wid][m*16 + (lane>>4)*4 + q] = p;
    }
  }
  __syncthreads();
  if (tid < 64){
    int r = brow + tid;
    if (r < Nrow){
      y0out[r] = shy[0][tid] + shy[1][tid] + b01[0];
      y1out[r] = shy[2][tid] + shy[3][tid] + b11[0];
    }
  }
}

// ================= fused propensity head ==============
// tile 128x128 (2x2 waves): s=sigmoid(v*psc+psb); ps=softmax(s@ps2W+ps2b)
__global__ __launch_bounds__(256,2) void ps_k(
    const ushort* __restrict__ A, int ldA,               // zcyh
    const ushort* __restrict__ W,                        // ps1T [128][128]
    const float* __restrict__ psc, const float* __restrict__ psb,
    const float* __restrict__ W2, const float* __restrict__ b2,
    float* __restrict__ psout, int Nrow)
{
  __shared__ __align__(16) ushort As[8192];
  __shared__ __align__(16) ushort Bs[8192];
  __shared__ float sh0[2][128];
  __shared__ float sh1[2][128];
  const int tid  = threadIdx.x;
  const int lane = tid & 63;
  const int wid  = __builtin_amdgcn_readfirstlane(tid >> 6);
  const int brow = blockIdx.x*128;
  const int wr = wid>>1, wc = wid&1;

  f32x4 acc[4][4];
#pragma unroll
  for(int m=0;m<4;m++)
#pragma unroll
    for(int n=0;n<4;n++) acc[m][n] = (f32x4){0.f,0.f,0.f,0.f};

  for (int kt=0; kt<2; ++kt){
    stage_tile<128>(A + (size_t)brow*ldA + kt*64, ldA, Nrow-1-brow, As, lane, wid);
    stage_tile<128>(W + kt*64, 128, 1<<30, Bs, lane, wid);
    __syncthreads();
#pragma unroll
    for (int kk=0;kk<2;kk++){
      short8 a[4], b[4];
#pragma unroll
      for (int m=0;m<4;m++) a[m] = fragld(As, wr*64 + m*16 + (lane&15), kk, lane);
#pragma unroll
      for (int n=0;n<4;n++) b[n] = fragld(Bs, wc*64 + n*16 + (lane&15), kk, lane);
#pragma unroll
      for (int m=0;m<4;m++)
#pragma unroll
        for (int n=0;n<4;n++)
          acc[m][n] = __builtin_amdgcn_mfma_f32_16x16x32_bf16(a[m], b[n], acc[m][n], 0,0,0);
    }
    __syncthreads();
  }
  float sc[4], sb[4], w0_[4], w1_[4];
#pragma unroll
  for (int n=0;n<4;n++){
    int c = wc*64 + n*16 + (lane&15);
    bool ok = (c<100);
    sc[n] = ok? psc[c] : 0.f;
    sb[n] = ok? psb[c] : 0.f;
    w0_[n]= ok? W2[2*c] : 0.f;
    w1_[n]= ok? W2[2*c+1] : 0.f;
  }
#pragma unroll
  for (int m=0;m<4;m++){
#pragma unroll
    for (int q=0;q<4;q++){
      float a0=0.f, a1=0.f;
#pragma unroll
      for (int n=0;n<4;n++){
        float s = sigf(acc[m][n][q]*sc[n] + sb[n]);
        a0 += s*w0_[n]; a1 += s*w1_[n];
      }
#pragma unroll
      for (int o=1;o<16;o<<=1){ a0 += __shfl_xor(a0,o); a1 += __shfl_xor(a1,o); }
      if ((lane&15)==0){
        int rt = wr*64 + m*16 + (lane>>4)*4 + q;
        sh0[wc][rt] = a0; sh1[wc][rt] = a1;
      }
    }
  }
  __syncthreads();
  if (tid < 128){
    int r = brow + tid;
    if (r < Nrow){
      float l0 = sh0[0][tid]+sh0[1][tid]+b2[0];
      float l1 = sh1[0][tid]+sh1[1][tid]+b2[1];
      float mx = fmaxf(l0,l1);
      float e0 = expf(l0-mx), e1 = expf(l1-mx);
      float inv = 1.f/(e0+e1);
      psout[(size_t)r*2]   = e0*inv;
      psout[(size_t)r*2+1] = e1*inv;
    }
  }
}

// ================= CSR build =================
__global__ void count_k(const int* __restrict__ ei, const float* __restrict__ ewl,
                        u64* __restrict__ degcnt)
{
  int idx = blockIdx.x*256 + threadIdx.x;
  if (idx >= TE) return;
  int t = idx / EE;
  int e = idx - t*EE;
  const int* dst = ei + (size_t)t*2*EE + EE;
  int d = dst[e];
  u64 v = (1ULL<<40) | (u64)(uint)(sigf(ewl[idx]) * 1048576.0f);
  atomicAdd((unsigned long long*)&degcnt[t*NN + d], (unsigned long long)v);
}

__global__ void dinv_k(const u64* __restrict__ degcnt, int* __restrict__ cnt,
                       float* __restrict__ dnv, float* __restrict__ invd){
  int idx = blockIdx.x*256+threadIdx.x;
  if (idx>=TN) return;
  u64 tot = degcnt[idx];
  int c = (int)(tot>>40);
  float S = (float)(tot & ((1ULL<<40)-1)) * (1.f/1048576.f);
  float dv = S + 1.f;
  cnt[idx] = c;
  dnv[idx]  = rsqrtf(dv);
  invd[idx] = 1.f/dv;
}

__global__ void scan1_k(const int* __restrict__ in, int* __restrict__ outv,
                        int* __restrict__ partials, int n)
{
  __shared__ int sh[256];
  int base = blockIdx.x*1024;
  int tid = threadIdx.x;
  int v[4]; int s=0;
#pragma unroll
  for (int i=0;i<4;i++){ int idx=base+tid*4+i; v[i] = (idx<n)? in[idx]:0; s+=v[i]; }
  sh[tid]=s; __syncthreads();
  for (int o=1;o<256;o<<=1){
    int t2 = (tid>=o)? sh[tid-o]:0;
    __syncthreads();
    sh[tid]+=t2;
    __syncthreads();
  }
  int excl = sh[tid]-s;
#pragma unroll
  for (int i=0;i<4;i++){ int idx=base+tid*4+i; if(idx<n) outv[idx]=excl; excl+=v[i]; }
  if (tid==255) partials[blockIdx.x]=sh[255];
}

__global__ void scan2_k(int* p, int np){
  __shared__ int sh[256];
  __shared__ int run;
  int tid=threadIdx.x;
  if(tid==0) run=0;
  __syncthreads();
  for(int base=0;base<np;base+=256){
    int v = (base+tid<np)? p[base+tid]:0;
    sh[tid]=v; __syncthreads();
    for(int o=1;o<256;o<<=1){
      int t2 = (tid>=o)? sh[tid-o]:0;
      __syncthreads();
      sh[tid]+=t2;
      __syncthreads();
    }
    int incl=sh[tid];
    int r0=run;
    __syncthreads();
    if(base+tid<np) p[base+tid]=r0+incl-v;
    __syncthreads();
    if(tid==0) run = r0 + sh[255];
    __syncthreads();
  }
}

__global__ void scan3_k(int* __restrict__ offs, const int* __restrict__ parts,
                        int* __restrict__ cur, int n){
  int idx = blockIdx.x*256+threadIdx.x;
  if (idx==0) offs[n] = TE;
  if (idx<n){ int v = offs[idx] + parts[idx>>10]; offs[idx]=v; cur[idx]=v; }
}

__global__ void fill_k(const int* __restrict__ ei, const float* __restrict__ ewl,
                       const float* __restrict__ dnv, int* __restrict__ cur,
                       u64* __restrict__ epack)
{
  int idx = blockIdx.x*256 + threadIdx.x;
  if (idx >= TE) return;
  int t = idx / EE;
  int e = idx - t*EE;
  const int* srcp = ei + (size_t)t*2*EE;
  const int* dstp = srcp + EE;
  int s=srcp[e], d=dstp[e];
  float nr = dnv[t*NN+s] * sigf(ewl[idx]) * dnv[t*NN+d];
  int pos = atomicAdd(&cur[t*NN+d], 1);
  epack[pos] = (u64)(uint)s | ((u64)__float_as_uint(nr) << 32);
}

// ================= GCN gather =================
__global__ __launch_bounds__(256) void gather_k(const int* __restrict__ offs_t,
    const u64* __restrict__ epack,
    const ushort* __restrict__ xwb, const float* __restrict__ invd_t,
    const float* __restrict__ gcb_t, ushort* __restrict__ rp)
{
  int node = blockIdx.x*4 + (threadIdx.x>>6);
  int lane = threadIdx.x & 63;
  if (node >= NN) return;
  int o0 = offs_t[node], o1 = offs_t[node+1];
  float a0=0.f, a1=0.f;
  int j=o0;
  for (; j+1<o1; j+=2){
    u64 e0 = epack[j], e1 = epack[j+1];
    uint r0 = ((const uint*)(xwb + ((size_t)(uint)e0)*128))[lane];
    uint r1 = ((const uint*)(xwb + ((size_t)(uint)e1)*128))[lane];
    float n0 = __uint_as_float((uint)(e0>>32));
    float n1 = __uint_as_float((uint)(e1>>32));
    a0 = fmaf(n0, b2f((ushort)(r0&0xffff)), a0);
    a1 = fmaf(n0, b2f((ushort)(r0>>16)),   a1);
    a0 = fmaf(n1, b2f((ushort)(r1&0xffff)), a0);
    a1 = fmaf(n1, b2f((ushort)(r1>>16)),   a1);
  }
  if (j<o1){
    u64 e0 = epack[j];
    uint r0 = ((const uint*)(xwb + ((size_t)(uint)e0)*128))[lane];
    float n0 = __uint_as_float((uint)(e0>>32));
    a0 = fmaf(n0, b2f((ushort)(r0&0xffff)), a0);
    a1 = fmaf(n0, b2f((ushort)(r0>>16)),   a1);
  }
  float sl = invd_t[node];
  uint us = ((const uint*)(xwb + (size_t)node*128))[lane];
  a0 = fmaf(sl, b2f((ushort)(us&0xffff)), a0) + gcb_t[2*lane];
  a1 = fmaf(sl, b2f((ushort)(us>>16)),   a1) + gcb_t[2*lane+1];
  a0 = fmaxf(a0, 0.f); a1 = fmaxf(a1, 0.f);
  uint pk = (uint)f2b(a0) | ((uint)f2b(a1) << 16);
  ((uint*)(rp + (size_t)node*384))[lane] = pk;
}

// ================= weight/activation prep =================
__global__ void convT_k(ushort* __restrict__ dst, const float* __restrict__ src,
                        int O, int Osrc, int K, int Kp)
{
  int idx = blockIdx.x*256 + threadIdx.x;
  if (idx >= O*Kp) return;
  dst += (size_t)blockIdx.y * O * Kp;
  src += (size_t)blockIdx.y * K * Osrc;
  int o = idx / Kp, k = idx - o*Kp;
  float v = (k<K && o<Osrc) ? src[(size_t)k*Osrc + o] : 0.f;
  dst[idx] = f2b(v);
}

__global__ void woc_k(ushort* __restrict__ dst, const float* __restrict__ o00W,
                      const float* __restrict__ o10W)
{
  int idx = blockIdx.x*256 + threadIdx.x;
  if (idx >= 256*128) return;
  int o = idx >> 7, k = idx & 127;
  float v = (o<128) ? o00W[(size_t)k*128 + o] : o10W[(size_t)k*128 + (o-128)];
  dst[idx] = f2b(v);
}

__global__ void wgru_k(const float* __restrict__ Wih, const float* __restrict__ Whh,
                       const float* __restrict__ bih, const float* __restrict__ bhh,
                       ushort* __restrict__ Wg, float* __restrict__ bg)
{
  int idx = blockIdx.x*256 + threadIdx.x;
  if (idx >= 1024*448) return;
  int c = idx/448, k = idx - c*448;
  int G = c>>6, g = (c>>4)&3, jj = c&15;
  int j = G*16 + jj;
  float v = 0.f;
  if (k < 152){
    if      (g==0) v = Wih[(size_t)j*152 + k];
    else if (g==1) v = Wih[(size_t)(256+j)*152 + k];
    else if (g==2) v = Wih[(size_t)(512+j)*152 + k];
  } else if (k >= 192){
    int kk = k-192;
    if      (g==0) v = Whh[(size_t)j*256 + kk];
    else if (g==1) v = Whh[(size_t)(256+j)*256 + kk];
    else if (g==3) v = Whh[(size_t)(512+j)*256 + kk];
  }
  Wg[idx] = f2b(v);
  if (k==0){
    float b;
    if      (g==0) b = bih[j]     + bhh[j];
    else if (g==1) b = bih[256+j] + bhh[256+j];
    else if (g==2) b = bih[512+j];
    else           b = bhh[512+j];
    bg[c] = b;
  }
}

__global__ void misc_k(const float* __restrict__ ps1b, const float* __restrict__ bng,
                       const float* __restrict__ bnb,
                       float* __restrict__ psc, float* __restrict__ psb)
{
  int i = threadIdx.x;
  if (i<100){ float sc = bng[i]*rsqrtf(1.f+1e-5f); psc[i]=sc; psb[i]=ps1b[i]*sc+bnb[i]; }
  else if (i<128){ psc[i]=0.f; psb[i]=0.f; }
}

__global__ void xconv_k(ushort* __restrict__ dst, const float* __restrict__ src, long n4)
{
  long i = (long)blockIdx.x*256 + threadIdx.x;
  if (i >= n4) return;
  float4 v = ((const float4*)src)[i];
  uint lo = (uint)f2b(v.x) | ((uint)f2b(v.y)<<16);
  uint hi = (uint)f2b(v.z) | ((uint)f2b(v.w)<<16);
  ((uint2*)dst)[i] = make_uint2(lo, hi);
}

__global__ void cyh_k(ushort* __restrict__ zcyh, const float* __restrict__ Cc,
                      const float* __restrict__ Yh)
{
  int gid = blockIdx.x*256 + threadIdx.x;   // NN*64
  int n = gid >> 6, l = gid & 63;
  if (n >= NN) return;
  float v = 0.f;
  if (l < 8)       v = Cc[(size_t)n*8 + l];
  else if (l < 24) v = Yh[(size_t)n*16 + (l-8)];
  zcyh[(size_t)n*192 + 128 + l] = f2b(v);
}

extern "C" void kernel_launch(void* const* d_in, const int* in_sizes, int n_in,
                              void* d_out_v, int out_size, void* d_ws, size_t ws_size,
                              hipStream_t stream)
{
  const float* X    = (const float*)d_in[0];
  const float* Cc   = (const float*)d_in[1];
  const float* Yh   = (const float*)d_in[2];
  const int*   EI   = (const int*)  d_in[3];
  const float* phiW = (const float*)d_in[4];  const float* phib = (const float*)d_in[5];
  const float* gcW  = (const float*)d_in[6];  const float* gcb  = (const float*)d_in[7];
  const float* ewl  = (const float*)d_in[8];
  const float* fuseW= (const float*)d_in[9];  const float* fuseb= (const float*)d_in[10];
  const float* o00W = (const float*)d_in[11]; const float* o00b = (const float*)d_in[12];
  const float* o10W = (const float*)d_in[13]; const float* o10b = (const float*)d_in[14];
  const float* o01W = (const float*)d_in[15]; const float* o01b = (const float*)d_in[16];
  const float* o11W = (const float*)d_in[17]; const float* o11b = (const float*)d_in[18];
  const float* ps1W = (const float*)d_in[19]; const float* ps1b = (const float*)d_in[20];
  const float* bng  = (const float*)d_in[21]; const float* bnb  = (const float*)d_in[22];
  const float* ps2W = (const float*)d_in[23]; const float* ps2b = (const float*)d_in[24];
  const float* Wih  = (const float*)d_in[25]; const float* Whh  = (const float*)d_in[26];
  const float* bih  = (const float*)d_in[27]; const float* bhh  = (const float*)d_in[28];
  float* out = (float*)d_out_v;

  char* wsb = (char*)d_ws;
  size_t off=0;
  auto alloc=[&](size_t bytes)->void*{
    void* p = wsb + off;
    off = (off + bytes + 255) & ~(size_t)255;
    return p;
  };
  u64*   degcnt= (u64*)  alloc((size_t)TN*8);
  int*   cnt   = (int*)  alloc((size_t)TN*4);
  int*   cur   = (int*)  alloc((size_t)TN*4);
  int*   offs  = (int*)  alloc(((size_t)TN+1)*4);
  float* dnv   = (float*)alloc((size_t)TN*4);
  float* invd  = (float*)alloc((size_t)TN*4);
  u64*   epack = (u64*)  alloc((size_t)TE*8);
  int*   parts = (int*)  alloc(4096);
  ushort* Xb   = (ushort*)alloc((size_t)T_STEPS*NN*128*2);
  ushort* rp   = (ushort*)alloc((size_t)NN*384*2);   // [rep(128) | phi(256)]
  ushort* zcyh = (ushort*)alloc((size_t)NN*192*2);   // [z(128) | c(8) | yh(16) | pad(40)]
  ushort* xwb  = (ushort*)alloc((size_t)NN*128*2);
  ushort* hbf0 = (ushort*)alloc((size_t)NN*256*2);
  ushort* hbf1 = (ushort*)alloc((size_t)NN*256*2);
  float* hb0   = (float*)alloc((size_t)NN*256*4);
  float* hb1   = (float*)alloc((size_t)NN*256*4);
  ushort* phiWt= (ushort*)alloc(256*128*2);
  ushort* gcWt = (ushort*)alloc((size_t)T_STEPS*128*256*2);
  ushort* fuseWt=(ushort*)alloc(128*640*2);
  ushort* Wgru = (ushort*)alloc((size_t)1024*448*2);
  float* bgru  = (float*)alloc(1024*4);
  ushort* wocT = (ushort*)alloc(256*128*2);
  ushort* ps1T = (ushort*)alloc(128*128*2);
  float* psc   = (float*)alloc(128*4);
  float* psb   = (float*)alloc(128*4);

  hipMemsetAsync(degcnt, 0, (size_t)TN*8, stream);
  hipMemsetAsync(hb0,  0, (size_t)NN*256*4, stream);
  hipMemsetAsync(hbf0, 0, (size_t)NN*256*2, stream);

  // --- prep ---
  misc_k<<<1,256,0,stream>>>(ps1b,bng,bnb,psc,psb);
  convT_k<<<dim3((256*128+255)/256,1),256,0,stream>>>(phiWt, phiW, 256,256,128,128);
  convT_k<<<dim3((128*256+255)/256,T_STEPS),256,0,stream>>>(gcWt, gcW, 128,128,256,256);
  convT_k<<<dim3((128*640+255)/256,1),256,0,stream>>>(fuseWt, fuseW, 128,128,640,640);
  convT_k<<<dim3((128*128+255)/256,1),256,0,stream>>>(ps1T, ps1W, 128,100,128,128);
  wgru_k<<<(1024*448+255)/256,256,0,stream>>>(Wih,Whh,bih,bhh,Wgru,bgru);
  woc_k<<<(256*128+255)/256,256,0,stream>>>(wocT, o00W, o10W);
  xconv_k<<<(int)(((size_t)T_STEPS*NN*128/4+255)/256),256,0,stream>>>(Xb, X, (long)T_STEPS*NN*128/4);

  // --- CSR build ---
  count_k<<<(TE+255)/256,256,0,stream>>>(EI,ewl,degcnt);
  dinv_k<<<(TN+255)/256,256,0,stream>>>(degcnt,cnt,dnv,invd);
  scan1_k<<<(TN+1023)/1024,256,0,stream>>>(cnt,offs,parts,TN);
  scan2_k<<<1,256,0,stream>>>(parts,(TN+1023)/1024);
  scan3_k<<<(TN+255)/256,256,0,stream>>>(offs,parts,cur,TN);
  fill_k<<<(TE+255)/256,256,0,stream>>>(EI,ewl,dnv,cur,epack);

  const size_t zoff  = (size_t)2*TN;
  const size_t psoff = zoff + (size_t)TN*128;
  const size_t hoff  = psoff + (size_t)TN*2;
  constexpr int GX = (NN+127)/128;                 // 391

  for (int t=0;t<T_STEPS;t++){
    const float*  hin  = (t&1)? hb1 : hb0;
    float*        hout = (t==T_STEPS-1)? (out+hoff) : ((t&1)? hb0 : hb1);
    const ushort* hbi  = (t&1)? hbf1 : hbf0;
    ushort*       hbo  = (t&1)? hbf0 : hbf1;
    float* zt = out + zoff + (size_t)t*NN*128;

    cyh_k<<<(NN*64+255)/256,256,0,stream>>>(zcyh, Cc+(size_t)t*NN*8, Yh+(size_t)t*NN*16);

    // phi = relu(X_t @ phi_W + b)   -> bf16 rp[:,128:384]
    gemm_bf<<<dim3(GX,2),256,0,stream>>>(Xb+(size_t)t*NN*128,128,128, nullptr,0,
      phiWt,128, phib,1, nullptr,0, rp+128,384, NN,256);
    // xw = phi @ gc_W[t]            -> bf16 xwb
    gemm_bf<<<dim3(GX,1),256,0,stream>>>(rp+128,384,256, nullptr,0,
      gcWt+(size_t)t*128*256,256, nullptr,0, nullptr,0, xwb,128, NN,128);
    // rep -> rp[:,0:128]
    gather_k<<<NN/4,256,0,stream>>>(offs+(size_t)t*NN, epack, xwb,
                                    invd+(size_t)t*NN, gcb+(size_t)t*128, rp);
    // z = relu([h,rep,phi]@fuseW+b) -> fp32 zt + bf16 zcyh[:,0:128]
    gemm_bf<<<dim3(GX,1),256,0,stream>>>(hbi,256,256, rp,384,
      fuseWt,640, fuseb,1, zt,128, zcyh,192, NN,128);
    // fused GRU: h_new
    gemm_gru<<<dim3(GX,8),256,0,stream>>>(zcyh,192,192, hbi,256,
      Wgru, bgru, hin, hout, hbo, NN);
    // fused outcome heads
    heads_k<<<(NN+63)/64,256,0,stream>>>(zcyh,192, wocT, o00b,o10b,
      o01W,o01b, o11W,o11b,
      out + TN + (size_t)t*NN,    // y0
      out + (size_t)t*NN, NN);    // y1
    // fused propensity head
    ps_k<<<GX,256,0,stream>>>(zcyh,192, ps1T, psc,psb, ps2W,ps2b,
      out+psoff+(size_t)t*NN*2, NN);
  }
  (void)in_sizes; (void)n_in; (void)out_size; (void)ws_size;
}

// Round 5
// 2697.293 us; speedup vs baseline: 6.4583x; 1.0523x over previous
//
#include <hip/hip_runtime.h>
#include <math.h>

#define T_STEPS 8
#define NN 50000
#define EE 800000
#define TN (T_STEPS*NN)   // 400000
#define TE (T_STEPS*EE)   // 6400000

typedef unsigned int uint;
typedef unsigned short ushort;
typedef unsigned long long u64;
typedef __attribute__((ext_vector_type(8))) short short8;
typedef __attribute__((ext_vector_type(4))) float f32x4;

__device__ __forceinline__ float sigf(float x){ return 1.0f/(1.0f+expf(-x)); }
__device__ __forceinline__ ushort f2b(float f){
  uint x = __float_as_uint(f);
  uint r = (x + 0x7fffu + ((x>>16)&1u)) >> 16;
  return (ushort)r;
}
__device__ __forceinline__ float b2f(ushort u){ return __uint_as_float(((uint)u)<<16); }

__device__ __forceinline__ void gload16(const ushort* g, ushort* l){
  __builtin_amdgcn_global_load_lds(
      (const __attribute__((address_space(1))) void*)g,
      (__attribute__((address_space(3))) void*)l, 16, 0, 0);
}

// stage ROWS x 64 bf16 tile into LDS (pre-swizzled source, linear dest)
template<int ROWS>
__device__ __forceinline__ void stage_tile(const ushort* base, int ld, int rowclamp,
                                           ushort* lds, int lane, int wid){
  constexpr int ITERS = ROWS/32;
#pragma unroll
  for (int i=0;i<ITERS;i++){
    int lin = i*256 + wid*64 + lane;
    int row = lin>>3, s = lin&7;
    int gr = row; if (gr > rowclamp) gr = rowclamp;
    const ushort* gp = base + (size_t)gr*ld + ((s ^ (row&7))<<3);
    gload16(gp, lds + (size_t)(i*256 + wid*64)*8);
  }
}

__device__ __forceinline__ short8 fragld(const ushort* lds, int R, int kk, int lane){
  int slot = (kk*4 + (lane>>4)) ^ (R&7);
  return *(const short8*)&lds[R*64 + slot*8];
}

struct Seg { const ushort* p; int ld; long ts; int w; };

// ================= generic bf16 MFMA GEMM (128x128 tile, 3-seg A, batched t) ======
__global__ __launch_bounds__(256,2) void gemm_bf(
    Seg s0, Seg s1, Seg s2,
    const ushort* __restrict__ W, int K2, long Wts,
    const float* __restrict__ bias, int act,
    const ushort* __restrict__ addp, int ldad, long adts,
    float* __restrict__ C32, int ldc, long c32ts,
    ushort* __restrict__ C16, int ldb, long c16ts,
    int Nrow, int NOvalid)
{
  __shared__ __align__(16) ushort As[8192];
  __shared__ __align__(16) ushort Bs[8192];
  const int t    = blockIdx.z;
  const int tid  = threadIdx.x;
  const int lane = tid & 63;
  const int wid  = __builtin_amdgcn_readfirstlane(tid >> 6);
  const int brow = blockIdx.x*128;
  const int bcol = blockIdx.y*128;
  const int wr = wid>>1, wc = wid&1;

  f32x4 acc[4][4];
#pragma unroll
  for(int m=0;m<4;m++)
#pragma unroll
    for(int n=0;n<4;n++) acc[m][n] = (f32x4){0.f,0.f,0.f,0.f};

  const int nk = K2 >> 6;
  for (int kt=0; kt<nk; ++kt){
    int col0 = kt*64;
    const ushort* ab; int ald;
    if (col0 < s0.w){ ab = s0.p + (size_t)t*s0.ts + col0; ald = s0.ld; }
    else if (col0 < s0.w + s1.w){ ab = s1.p + (size_t)t*s1.ts + (col0 - s0.w); ald = s1.ld; }
    else { ab = s2.p + (size_t)t*s2.ts + (col0 - s0.w - s1.w); ald = s2.ld; }
    stage_tile<128>(ab + (size_t)brow*ald, ald, Nrow-1-brow, As, lane, wid);
    stage_tile<128>(W + (size_t)t*Wts + (size_t)bcol*K2 + col0, K2, 1<<30, Bs, lane, wid);
    __syncthreads();
#pragma unroll
    for (int kk=0;kk<2;kk++){
      short8 a[4], b[4];
#pragma unroll
      for (int m=0;m<4;m++) a[m] = fragld(As, wr*64 + m*16 + (lane&15), kk, lane);
#pragma unroll
      for (int n=0;n<4;n++) b[n] = fragld(Bs, wc*64 + n*16 + (lane&15), kk, lane);
#pragma unroll
      for (int m=0;m<4;m++)
#pragma unroll
        for (int n=0;n<4;n++)
          acc[m][n] = __builtin_amdgcn_mfma_f32_16x16x32_bf16(a[m], b[n], acc[m][n], 0,0,0);
    }
    __syncthreads();
  }
  const int rbase = brow + wr*64 + (lane>>4)*4;
  const int cbase = bcol + wc*64 + (lane&15);
#pragma unroll
  for (int m=0;m<4;m++){
#pragma unroll
    for (int q=0;q<4;q++){
      int r = rbase + m*16 + q;
      if (r >= Nrow) continue;
#pragma unroll
      for (int n=0;n<4;n++){
        int c = cbase + n*16;
        if (c >= NOvalid) continue;
        float v = acc[m][n][q];
        if (addp) v += b2f(addp[(size_t)t*adts + (size_t)r*ldad + c]);
        if (bias) v += bias[c];
        if (act==1) v = fmaxf(v, 0.f);
        if (C32) C32[(size_t)t*c32ts + (size_t)r*ldc + c] = v;
        if (C16) C16[(size_t)t*c16ts + (size_t)r*ldb + c] = f2b(v);
      }
    }
  }
}

// ================= fused GRU GEMM: [z | cyh | h] @ Wgru^T -> gates -> h_new =======
__global__ __launch_bounds__(256,2) void gemm_gru(
    Seg s0, Seg s1, Seg s2,
    const ushort* __restrict__ W,                        // Wgru [1024][448]
    const float* __restrict__ bg,                        // [1024]
    const float* __restrict__ hin,                       // fp32 h_t
    float* __restrict__ hout, ushort* __restrict__ hbfo, // hbfo != s2.p (ping-pong!)
    int Nrow)
{
  __shared__ __align__(16) ushort As[8192];
  __shared__ __align__(16) ushort Bs[8192];
  const int tid  = threadIdx.x;
  const int lane = tid & 63;
  const int wid  = __builtin_amdgcn_readfirstlane(tid >> 6);
  const int brow = blockIdx.x*128;
  const int bcol = blockIdx.y*128;
  const int wr = wid>>1, wc = wid&1;
  const int K2 = 448;

  f32x4 acc[4][4];
#pragma unroll
  for(int m=0;m<4;m++)
#pragma unroll
    for(int n=0;n<4;n++) acc[m][n] = (f32x4){0.f,0.f,0.f,0.f};

  for (int kt=0; kt<7; ++kt){
    int col0 = kt*64;
    const ushort* ab; int ald;
    if (col0 < s0.w){ ab = s0.p + col0; ald = s0.ld; }
    else if (col0 < s0.w + s1.w){ ab = s1.p + (col0 - s0.w); ald = s1.ld; }
    else { ab = s2.p + (col0 - s0.w - s1.w); ald = s2.ld; }
    stage_tile<128>(ab + (size_t)brow*ald, ald, Nrow-1-brow, As, lane, wid);
    stage_tile<128>(W + (size_t)bcol*K2 + col0, K2, 1<<30, Bs, lane, wid);
    __syncthreads();
#pragma unroll
    for (int kk=0;kk<2;kk++){
      short8 a[4], b[4];
#pragma unroll
      for (int m=0;m<4;m++) a[m] = fragld(As, wr*64 + m*16 + (lane&15), kk, lane);
#pragma unroll
      for (int n=0;n<4;n++) b[n] = fragld(Bs, wc*64 + n*16 + (lane&15), kk, lane);
#pragma unroll
      for (int m=0;m<4;m++)
#pragma unroll
        for (int n=0;n<4;n++)
          acc[m][n] = __builtin_amdgcn_mfma_f32_16x16x32_bf16(a[m], b[n], acc[m][n], 0,0,0);
    }
    __syncthreads();
  }
  const int jj = lane&15;
  const int j  = blockIdx.y*32 + wc*16 + jj;       // hidden unit index
  const int rbase = brow + wr*64 + (lane>>4)*4;
  const int bcolw = bcol + wc*64;
  float bb[4];
#pragma unroll
  for (int n=0;n<4;n++) bb[n] = bg[bcolw + n*16 + jj];
#pragma unroll
  for (int m=0;m<4;m++){
#pragma unroll
    for (int q=0;q<4;q++){
      int r = rbase + m*16 + q;
      if (r >= Nrow) continue;
      float v0 = acc[m][0][q] + bb[0];
      float v1 = acc[m][1][q] + bb[1];
      float v2 = acc[m][2][q] + bb[2];
      float v3 = acc[m][3][q] + bb[3];
      float rg = sigf(v0), ug = sigf(v1);
      float ng = tanhf(v2 + rg*v3);
      float ho = hin[(size_t)r*256 + j];
      float hn = (1.f-ug)*ng + ug*ho;
      hout[(size_t)r*256 + j] = hn;
      hbfo[(size_t)r*256 + j] = f2b(hn);
    }
  }
}

// ================= fused outcome heads (batched over t) ==============
__global__ __launch_bounds__(256,2) void heads_k(
    const ushort* __restrict__ Az, long Ats,             // zbf_all, ld 128
    const ushort* __restrict__ W,                        // wocT [256][128]
    const float* __restrict__ o00b, const float* __restrict__ o10b,
    const float* __restrict__ w01, const float* __restrict__ b01,
    const float* __restrict__ w11, const float* __restrict__ b11,
    float* __restrict__ y0out, long y0ts,
    float* __restrict__ y1out, long y1ts, int Nrow)
{
  __shared__ __align__(16) ushort As[4096];
  __shared__ __align__(16) ushort Bs[16384];
  __shared__ float shy[4][64];
  const int t    = blockIdx.z;
  const int tid  = threadIdx.x;
  const int lane = tid & 63;
  const int wid  = __builtin_amdgcn_readfirstlane(tid >> 6);
  const int brow = blockIdx.x*64;
  const ushort* A = Az + (size_t)t*Ats;

  f32x4 acc[4][4];
#pragma unroll
  for(int m=0;m<4;m++)
#pragma unroll
    for(int n=0;n<4;n++) acc[m][n] = (f32x4){0.f,0.f,0.f,0.f};

  for (int kt=0; kt<2; ++kt){
    stage_tile<64>(A + (size_t)brow*128 + kt*64, 128, Nrow-1-brow, As, lane, wid);
    stage_tile<256>(W + kt*64, 128, 1<<30, Bs, lane, wid);
    __syncthreads();
#pragma unroll
    for (int kk=0;kk<2;kk++){
      short8 a[4], b[4];
#pragma unroll
      for (int m=0;m<4;m++) a[m] = fragld(As, m*16 + (lane&15), kk, lane);
#pragma unroll
      for (int n=0;n<4;n++) b[n] = fragld(Bs, wid*64 + n*16 + (lane&15), kk, lane);
#pragma unroll
      for (int m=0;m<4;m++)
#pragma unroll
        for (int n=0;n<4;n++)
          acc[m][n] = __builtin_amdgcn_mfma_f32_16x16x32_bf16(a[m], b[n], acc[m][n], 0,0,0);
    }
    __syncthreads();
  }
  float bb[4], ww[4];
#pragma unroll
  for (int n=0;n<4;n++){
    int c = wid*64 + n*16 + (lane&15);
    bb[n] = (c<128)? o00b[c] : o10b[c-128];
    ww[n] = (c<128)? w01[c]  : w11[c-128];
  }
#pragma unroll
  for (int m=0;m<4;m++){
#pragma unroll
    for (int q=0;q<4;q++){
      float p = 0.f;
#pragma unroll
      for (int n=0;n<4;n++) p += fmaxf(acc[m][n][q] + bb[n], 0.f) * ww[n];
#pragma unroll
      for (int o=1;o<16;o<<=1) p += __shfl_xor(p, o);
      if ((lane&15)==0) shy[wid][m*16 + (lane>>4)*4 + q] = p;
    }
  }
  __syncthreads();
  if (tid < 64){
    int r = brow + tid;
    if (r < Nrow){
      y0out[(size_t)t*y0ts + r] = shy[0][tid] + shy[1][tid] + b01[0];
      y1out[(size_t)t*y1ts + r] = shy[2][tid] + shy[3][tid] + b11[0];
    }
  }
}

// ================= fused propensity head (batched over t) ==============
__global__ __launch_bounds__(256,2) void ps_k(
    const ushort* __restrict__ Az, long Ats,             // zbf_all, ld 128
    const ushort* __restrict__ W,                        // ps1T [128][128]
    const float* __restrict__ psc, const float* __restrict__ psb,
    const float* __restrict__ W2, const float* __restrict__ b2,
    float* __restrict__ psout, long psts, int Nrow)
{
  __shared__ __align__(16) ushort As[8192];
  __shared__ __align__(16) ushort Bs[8192];
  __shared__ float sh0[2][128];
  __shared__ float sh1[2][128];
  const int t    = blockIdx.z;
  const int tid  = threadIdx.x;
  const int lane = tid & 63;
  const int wid  = __builtin_amdgcn_readfirstlane(tid >> 6);
  const int brow = blockIdx.x*128;
  const int wr = wid>>1, wc = wid&1;
  const ushort* A = Az + (size_t)t*Ats;

  f32x4 acc[4][4];
#pragma unroll
  for(int m=0;m<4;m++)
#pragma unroll
    for(int n=0;n<4;n++) acc[m][n] = (f32x4){0.f,0.f,0.f,0.f};

  for (int kt=0; kt<2; ++kt){
    stage_tile<128>(A + (size_t)brow*128 + kt*64, 128, Nrow-1-brow, As, lane, wid);
    stage_tile<128>(W + kt*64, 128, 1<<30, Bs, lane, wid);
    __syncthreads();
#pragma unroll
    for (int kk=0;kk<2;kk++){
      short8 a[4], b[4];
#pragma unroll
      for (int m=0;m<4;m++) a[m] = fragld(As, wr*64 + m*16 + (lane&15), kk, lane);
#pragma unroll
      for (int n=0;n<4;n++) b[n] = fragld(Bs, wc*64 + n*16 + (lane&15), kk, lane);
#pragma unroll
      for (int m=0;m<4;m++)
#pragma unroll
        for (int n=0;n<4;n++)
          acc[m][n] = __builtin_amdgcn_mfma_f32_16x16x32_bf16(a[m], b[n], acc[m][n], 0,0,0);
    }
    __syncthreads();
  }
  float sc[4], sb[4], w0_[4], w1_[4];
#pragma unroll
  for (int n=0;n<4;n++){
    int c = wc*64 + n*16 + (lane&15);
    bool ok = (c<100);
    sc[n] = ok? psc[c] : 0.f;
    sb[n] = ok? psb[c] : 0.f;
    w0_[n]= ok? W2[2*c] : 0.f;
    w1_[n]= ok? W2[2*c+1] : 0.f;
  }
#pragma unroll
  for (int m=0;m<4;m++){
#pragma unroll
    for (int q=0;q<4;q++){
      float a0=0.f, a1=0.f;
#pragma unroll
      for (int n=0;n<4;n++){
        float s = sigf(acc[m][n][q]*sc[n] + sb[n]);
        a0 += s*w0_[n]; a1 += s*w1_[n];
      }
#pragma unroll
      for (int o=1;o<16;o<<=1){ a0 += __shfl_xor(a0,o); a1 += __shfl_xor(a1,o); }
      if ((lane&15)==0){
        int rt = wr*64 + m*16 + (lane>>4)*4 + q;
        sh0[wc][rt] = a0; sh1[wc][rt] = a1;
      }
    }
  }
  __syncthreads();
  if (tid < 128){
    int r = brow + tid;
    if (r < Nrow){
      float l0 = sh0[0][tid]+sh0[1][tid]+b2[0];
      float l1 = sh1[0][tid]+sh1[1][tid]+b2[1];
      float mx = fmaxf(l0,l1);
      float e0 = expf(l0-mx), e1 = expf(l1-mx);
      float inv = 1.f/(e0+e1);
      psout[(size_t)t*psts + (size_t)r*2]   = e0*inv;
      psout[(size_t)t*psts + (size_t)r*2+1] = e1*inv;
    }
  }
}

// ================= CSR build =================
__global__ void count_k(const int* __restrict__ ei, const float* __restrict__ ewl,
                        u64* __restrict__ degcnt)
{
  int idx = blockIdx.x*256 + threadIdx.x;
  if (idx >= TE) return;
  int t = idx / EE;
  int e = idx - t*EE;
  const int* dst = ei + (size_t)t*2*EE + EE;
  int d = dst[e];
  u64 v = (1ULL<<40) | (u64)(uint)(sigf(ewl[idx]) * 1048576.0f);
  atomicAdd((unsigned long long*)&degcnt[t*NN + d], (unsigned long long)v);
}

__global__ void dinv_k(const u64* __restrict__ degcnt, int* __restrict__ cnt,
                       float* __restrict__ dnv, float* __restrict__ invd){
  int idx = blockIdx.x*256+threadIdx.x;
  if (idx>=TN) return;
  u64 tot = degcnt[idx];
  int c = (int)(tot>>40);
  float S = (float)(tot & ((1ULL<<40)-1)) * (1.f/1048576.f);
  float dv = S + 1.f;
  cnt[idx] = c;
  dnv[idx]  = rsqrtf(dv);
  invd[idx] = 1.f/dv;
}

__global__ void scan1_k(const int* __restrict__ in, int* __restrict__ outv,
                        int* __restrict__ partials, int n)
{
  __shared__ int sh[256];
  int base = blockIdx.x*1024;
  int tid = threadIdx.x;
  int v[4]; int s=0;
#pragma unroll
  for (int i=0;i<4;i++){ int idx=base+tid*4+i; v[i] = (idx<n)? in[idx]:0; s+=v[i]; }
  sh[tid]=s; __syncthreads();
  for (int o=1;o<256;o<<=1){
    int t2 = (tid>=o)? sh[tid-o]:0;
    __syncthreads();
    sh[tid]+=t2;
    __syncthreads();
  }
  int excl = sh[tid]-s;
#pragma unroll
  for (int i=0;i<4;i++){ int idx=base+tid*4+i; if(idx<n) outv[idx]=excl; excl+=v[i]; }
  if (tid==255) partials[blockIdx.x]=sh[255];
}

__global__ void scan2_k(int* p, int np){
  __shared__ int sh[256];
  __shared__ int run;
  int tid=threadIdx.x;
  if(tid==0) run=0;
  __syncthreads();
  for(int base=0;base<np;base+=256){
    int v = (base+tid<np)? p[base+tid]:0;
    sh[tid]=v; __syncthreads();
    for(int o=1;o<256;o<<=1){
      int t2 = (tid>=o)? sh[tid-o]:0;
      __syncthreads();
      sh[tid]+=t2;
      __syncthreads();
    }
    int incl=sh[tid];
    int r0=run;
    __syncthreads();
    if(base+tid<np) p[base+tid]=r0+incl-v;
    __syncthreads();
    if(tid==0) run = r0 + sh[255];
    __syncthreads();
  }
}

__global__ void scan3_k(int* __restrict__ offs, const int* __restrict__ parts,
                        int* __restrict__ cur, int n){
  int idx = blockIdx.x*256+threadIdx.x;
  if (idx==0) offs[n] = TE;
  if (idx<n){ int v = offs[idx] + parts[idx>>10]; offs[idx]=v; cur[idx]=v; }
}

__global__ void fill_k(const int* __restrict__ ei, const float* __restrict__ ewl,
                       const float* __restrict__ dnv, int* __restrict__ cur,
                       uint* __restrict__ epack)
{
  int idx = blockIdx.x*256 + threadIdx.x;
  if (idx >= TE) return;
  int t = idx / EE;
  int e = idx - t*EE;
  const int* srcp = ei + (size_t)t*2*EE;
  const int* dstp = srcp + EE;
  int s=srcp[e], d=dstp[e];
  float nr = dnv[t*NN+s] * sigf(ewl[idx]) * dnv[t*NN+d];
  uint nq = (uint)(nr*65535.f + 0.5f);
  int pos = atomicAdd(&cur[t*NN+d], 1);
  epack[pos] = (uint)s | (nq<<16);
}

// ================= GCN gather (batched over t) =================
__global__ __launch_bounds__(256) void gather_k(const int* __restrict__ offs,
    const uint* __restrict__ epack,
    const ushort* __restrict__ xwb, const float* __restrict__ invd,
    const float* __restrict__ gcb, ushort* __restrict__ rep)
{
  int t    = blockIdx.z;
  int node = blockIdx.x*4 + (threadIdx.x>>6);
  int lane = threadIdx.x & 63;
  if (node >= NN) return;
  const int* offs_t = offs + (size_t)t*NN;
  const ushort* xw_t = xwb + (size_t)t*NN*128;
  int o0 = offs_t[node], o1 = offs_t[node+1];
  float a0=0.f, a1=0.f;
  int j=o0;
  for (; j+1<o1; j+=2){
    uint e0 = epack[j], e1 = epack[j+1];
    uint r0 = ((const uint*)(xw_t + ((size_t)(e0&0xffff))*128))[lane];
    uint r1 = ((const uint*)(xw_t + ((size_t)(e1&0xffff))*128))[lane];
    float n0 = (float)(e0>>16) * (1.f/65535.f);
    float n1 = (float)(e1>>16) * (1.f/65535.f);
    a0 = fmaf(n0, b2f((ushort)(r0&0xffff)), a0);
    a1 = fmaf(n0, b2f((ushort)(r0>>16)),   a1);
    a0 = fmaf(n1, b2f((ushort)(r1&0xffff)), a0);
    a1 = fmaf(n1, b2f((ushort)(r1>>16)),   a1);
  }
  if (j<o1){
    uint e0 = epack[j];
    uint r0 = ((const uint*)(xw_t + ((size_t)(e0&0xffff))*128))[lane];
    float n0 = (float)(e0>>16) * (1.f/65535.f);
    a0 = fmaf(n0, b2f((ushort)(r0&0xffff)), a0);
    a1 = fmaf(n0, b2f((ushort)(r0>>16)),   a1);
  }
  float sl = invd[(size_t)t*NN + node];
  const float* gcb_t = gcb + (size_t)t*128;
  uint us = ((const uint*)(xw_t + (size_t)node*128))[lane];
  a0 = fmaf(sl, b2f((ushort)(us&0xffff)), a0) + gcb_t[2*lane];
  a1 = fmaf(sl, b2f((ushort)(us>>16)),   a1) + gcb_t[2*lane+1];
  a0 = fmaxf(a0, 0.f); a1 = fmaxf(a1, 0.f);
  uint pk = (uint)f2b(a0) | ((uint)f2b(a1) << 16);
  ((uint*)(rep + ((size_t)t*NN + node)*128))[lane] = pk;
}

// ================= weight/activation prep =================
__global__ void convT_k(ushort* __restrict__ dst, const float* __restrict__ src,
                        int O, int Osrc, int K, int Kp)
{
  int idx = blockIdx.x*256 + threadIdx.x;
  if (idx >= O*Kp) return;
  dst += (size_t)blockIdx.y * O * Kp;
  src += (size_t)blockIdx.y * K * Osrc;
  int o = idx / Kp, k = idx - o*Kp;
  float v = (k<K && o<Osrc) ? src[(size_t)k*Osrc + o] : 0.f;
  dst[idx] = f2b(v);
}

__global__ void woc_k(ushort* __restrict__ dst, const float* __restrict__ o00W,
                      const float* __restrict__ o10W)
{
  int idx = blockIdx.x*256 + threadIdx.x;
  if (idx >= 256*128) return;
  int o = idx >> 7, k = idx & 127;
  float v = (o<128) ? o00W[(size_t)k*128 + o] : o10W[(size_t)k*128 + (o-128)];
  dst[idx] = f2b(v);
}

__global__ void wgru_k(const float* __restrict__ Wih, const float* __restrict__ Whh,
                       const float* __restrict__ bih, const float* __restrict__ bhh,
                       ushort* __restrict__ Wg, float* __restrict__ bg)
{
  int idx = blockIdx.x*256 + threadIdx.x;
  if (idx >= 1024*448) return;
  int c = idx/448, k = idx - c*448;
  int G = c>>6, g = (c>>4)&3, jj = c&15;
  int j = G*16 + jj;
  float v = 0.f;
  if (k < 152){
    if      (g==0) v = Wih[(size_t)j*152 + k];
    else if (g==1) v = Wih[(size_t)(256+j)*152 + k];
    else if (g==2) v = Wih[(size_t)(512+j)*152 + k];
  } else if (k >= 192){
    int kk = k-192;
    if      (g==0) v = Whh[(size_t)j*256 + kk];
    else if (g==1) v = Whh[(size_t)(256+j)*256 + kk];
    else if (g==3) v = Whh[(size_t)(512+j)*256 + kk];
  }
  Wg[idx] = f2b(v);
  if (k==0){
    float b;
    if      (g==0) b = bih[j]     + bhh[j];
    else if (g==1) b = bih[256+j] + bhh[256+j];
    else if (g==2) b = bih[512+j];
    else           b = bhh[512+j];
    bg[c] = b;
  }
}

__global__ void misc_k(const float* __restrict__ ps1b, const float* __restrict__ bng,
                       const float* __restrict__ bnb,
                       float* __restrict__ psc, float* __restrict__ psb)
{
  int i = threadIdx.x;
  if (i<100){ float sc = bng[i]*rsqrtf(1.f+1e-5f); psc[i]=sc; psb[i]=ps1b[i]*sc+bnb[i]; }
  else if (i<128){ psc[i]=0.f; psb[i]=0.f; }
}

__global__ void xconv_k(ushort* __restrict__ dst, const float* __restrict__ src, long n4)
{
  long i = (long)blockIdx.x*256 + threadIdx.x;
  if (i >= n4) return;
  float4 v = ((const float4*)src)[i];
  uint lo = (uint)f2b(v.x) | ((uint)f2b(v.y)<<16);
  uint hi = (uint)f2b(v.z) | ((uint)f2b(v.w)<<16);
  ((uint2*)dst)[i] = make_uint2(lo, hi);
}

// fill cyh_all[g][0:64] = [c(8) | yh(16) | zeros(40)] for all g = t*NN+n
__global__ void cyh_k(ushort* __restrict__ cyh, const float* __restrict__ Cc,
                      const float* __restrict__ Yh)
{
  long gid = (long)blockIdx.x*256 + threadIdx.x;   // TN*64
  if (gid >= (long)TN*64) return;
  long g = gid >> 6; int l = (int)(gid & 63);
  float v = 0.f;
  if (l < 8)       v = Cc[g*8 + l];
  else if (l < 24) v = Yh[g*16 + (l-8)];
  cyh[g*64 + l] = f2b(v);
}

extern "C" void kernel_launch(void* const* d_in, const int* in_sizes, int n_in,
                              void* d_out_v, int out_size, void* d_ws, size_t ws_size,
                              hipStream_t stream)
{
  const float* X    = (const float*)d_in[0];
  const float* Cc   = (const float*)d_in[1];
  const float* Yh   = (const float*)d_in[2];
  const int*   EI   = (const int*)  d_in[3];
  const float* phiW = (const float*)d_in[4];  const float* phib = (const float*)d_in[5];
  const float* gcW  = (const float*)d_in[6];  const float* gcb  = (const float*)d_in[7];
  const float* ewl  = (const float*)d_in[8];
  const float* fuseW= (const float*)d_in[9];  const float* fuseb= (const float*)d_in[10];
  const float* o00W = (const float*)d_in[11]; const float* o00b = (const float*)d_in[12];
  const float* o10W = (const float*)d_in[13]; const float* o10b = (const float*)d_in[14];
  const float* o01W = (const float*)d_in[15]; const float* o01b = (const float*)d_in[16];
  const float* o11W = (const float*)d_in[17]; const float* o11b = (const float*)d_in[18];
  const float* ps1W = (const float*)d_in[19]; const float* ps1b = (const float*)d_in[20];
  const float* bng  = (const float*)d_in[21]; const float* bnb  = (const float*)d_in[22];
  const float* ps2W = (const float*)d_in[23]; const float* ps2b = (const float*)d_in[24];
  const float* Wih  = (const float*)d_in[25]; const float* Whh  = (const float*)d_in[26];
  const float* bih  = (const float*)d_in[27]; const float* bhh  = (const float*)d_in[28];
  float* out = (float*)d_out_v;

  char* wsb = (char*)d_ws;
  size_t off=0;
  auto alloc=[&](size_t bytes)->void*{
    void* p = wsb + off;
    off = (off + bytes + 255) & ~(size_t)255;
    return p;
  };
  u64*   degcnt= (u64*)  alloc((size_t)TN*8);
  int*   cnt   = (int*)  alloc((size_t)TN*4);
  int*   cur   = (int*)  alloc((size_t)TN*4);
  int*   offs  = (int*)  alloc(((size_t)TN+1)*4);
  float* dnv   = (float*)alloc((size_t)TN*4);
  float* invd  = (float*)alloc((size_t)TN*4);
  uint*  epack = (uint*) alloc((size_t)TE*4);
  int*   parts = (int*)  alloc(4096);
  ushort* Xb   = (ushort*)alloc((size_t)TN*128*2);   // -> rep_all after phi GEMM
  ushort* phiA = (ushort*)alloc((size_t)TN*256*2);   // -> zbf_all + cyh_all after pz
  ushort* xwb  = (ushort*)alloc((size_t)TN*128*2);
  ushort* pz   = (ushort*)alloc((size_t)TN*128*2);
  ushort* hbf0 = (ushort*)alloc((size_t)NN*256*2);   // bf16 h ping-pong
  ushort* hbf1 = (ushort*)alloc((size_t)NN*256*2);
  float*  hb   = (float*)alloc((size_t)NN*256*4);    // fp32 h (in-place safe)
  ushort* phiWt= (ushort*)alloc(256*128*2);
  ushort* gcWt = (ushort*)alloc((size_t)T_STEPS*128*256*2);
  ushort* WhT  = (ushort*)alloc(128*256*2);
  ushort* WrpT = (ushort*)alloc(128*384*2);
  ushort* Wgru = (ushort*)alloc((size_t)1024*448*2);
  float* bgru  = (float*)alloc(1024*4);
  ushort* wocT = (ushort*)alloc(256*128*2);
  ushort* ps1T = (ushort*)alloc(128*128*2);
  float* psc   = (float*)alloc(128*4);
  float* psb   = (float*)alloc(128*4);

  ushort* rep_all = Xb;                              // TN x 128 (alias)
  ushort* zbf     = phiA;                            // TN x 128 (alias)
  ushort* cyh     = phiA + (size_t)TN*128;           // TN x 64  (alias)

  hipMemsetAsync(degcnt, 0, (size_t)TN*8, stream);
  hipMemsetAsync(hb,   0, (size_t)NN*256*4, stream);
  hipMemsetAsync(hbf0, 0, (size_t)NN*256*2, stream);

  // --- prep ---
  misc_k<<<1,256,0,stream>>>(ps1b,bng,bnb,psc,psb);
  convT_k<<<dim3((256*128+255)/256,1),256,0,stream>>>(phiWt, phiW, 256,256,128,128);
  convT_k<<<dim3((128*256+255)/256,T_STEPS),256,0,stream>>>(gcWt, gcW, 128,128,256,256);
  convT_k<<<dim3((128*256+255)/256,1),256,0,stream>>>(WhT, fuseW, 128,128,256,256);
  convT_k<<<dim3((128*384+255)/256,1),256,0,stream>>>(WrpT, fuseW+256*128, 128,128,384,384);
  convT_k<<<dim3((128*128+255)/256,1),256,0,stream>>>(ps1T, ps1W, 128,100,128,128);
  wgru_k<<<(1024*448+255)/256,256,0,stream>>>(Wih,Whh,bih,bhh,Wgru,bgru);
  woc_k<<<(256*128+255)/256,256,0,stream>>>(wocT, o00W, o10W);
  xconv_k<<<(int)(((size_t)TN*128/4+255)/256),256,0,stream>>>(Xb, X, (long)TN*128/4);

  // --- CSR build ---
  count_k<<<(TE+255)/256,256,0,stream>>>(EI,ewl,degcnt);
  dinv_k<<<(TN+255)/256,256,0,stream>>>(degcnt,cnt,dnv,invd);
  scan1_k<<<(TN+1023)/1024,256,0,stream>>>(cnt,offs,parts,TN);
  scan2_k<<<1,256,0,stream>>>(parts,(TN+1023)/1024);
  scan3_k<<<(TN+255)/256,256,0,stream>>>(offs,parts,cur,TN);
  fill_k<<<(TE+255)/256,256,0,stream>>>(EI,ewl,dnv,cur,epack);

  const size_t zoff  = (size_t)2*TN;
  const size_t psoff = zoff + (size_t)TN*128;
  const size_t hoff  = psoff + (size_t)TN*2;
  constexpr int GX = (NN+127)/128;                 // 391
  const Seg S0 = {nullptr,0,0,0};

  // --- batched recurrence-free work ---
  // phi_all = relu(X_t @ phi_W + b)
  gemm_bf<<<dim3(GX,2,8),256,0,stream>>>(
    Seg{Xb,128,(long)NN*128,128}, S0, S0, phiWt,128,0, phib,1,
    nullptr,0,0, nullptr,0,0, phiA,256,(long)NN*256, NN,256);
  // xw_all = phi_all @ gc_W[t]
  gemm_bf<<<dim3(GX,1,8),256,0,stream>>>(
    Seg{phiA,256,(long)NN*256,256}, S0, S0, gcWt,256,(long)128*256, nullptr,0,
    nullptr,0,0, nullptr,0,0, xwb,128,(long)NN*128, NN,128);
  // rep_all (overwrites Xb region; phi GEMM already consumed Xb)
  gather_k<<<dim3(NN/4,1,8),256,0,stream>>>(offs, epack, xwb, invd, gcb, rep_all);
  // pz_all = [rep_all | phi_all] @ [Wr;Wp]  (single fp32 accum, one bf16 rounding)
  gemm_bf<<<dim3(GX,1,8),256,0,stream>>>(
    Seg{rep_all,128,(long)NN*128,128}, Seg{phiA,256,(long)NN*256,256}, S0,
    WrpT,384,0, nullptr,0,
    nullptr,0,0, nullptr,0,0, pz,128,(long)NN*128, NN,128);
  // cyh_all (overwrites upper phiA region; phi_all dead after pz)
  cyh_k<<<(int)(((long)TN*64+255)/256),256,0,stream>>>(cyh, Cc, Yh);

  // --- recurrent chain ---
  for (int t=0;t<T_STEPS;t++){
    const ushort* hbi = (t&1)? hbf1 : hbf0;
    ushort*       hbo = (t&1)? hbf0 : hbf1;
    float* hout = (t==T_STEPS-1)? (out+hoff) : hb;
    float* zt = out + zoff + (size_t)t*NN*128;
    ushort* zbt = zbf + (size_t)t*NN*128;
    // z = relu(h@Wh + pz_t + fuse_b) -> fp32 zt + bf16 zbf_t
    gemm_bf<<<dim3(GX,1,1),256,0,stream>>>(
      Seg{hbi,256,0,256}, S0, S0, WhT,256,0, fuseb,1,
      pz + (size_t)t*NN*128,128,0, zt,128,0, zbt,128,0, NN,128);
    // fused GRU -> h (fp32 in-place, bf16 ping-pong)
    gemm_gru<<<dim3(GX,8),256,0,stream>>>(
      Seg{zbt,128,0,128}, Seg{cyh + (size_t)t*NN*64,64,0,64}, Seg{hbi,256,0,256},
      Wgru, bgru, hb, hout, hbo, NN);
  }

  // --- batched heads ---
  heads_k<<<dim3((NN+63)/64,1,8),256,0,stream>>>(
    zbf,(long)NN*128, wocT, o00b,o10b, o01W,o01b, o11W,o11b,
    out + TN, (long)NN,     // y0
    out, (long)NN, NN);     // y1
  ps_k<<<dim3(GX,1,8),256,0,stream>>>(
    zbf,(long)NN*128, ps1T, psc,psb, ps2W,ps2b,
    out+psoff, (long)NN*2, NN);

  (void)in_sizes; (void)n_in; (void)out_size; (void)ws_size;
}

// Round 6
// 2570.132 us; speedup vs baseline: 6.7779x; 1.0495x over previous
//
#include <hip/hip_runtime.h>
#include <math.h>

#define T_STEPS 8
#define NN 50000
#define EE 800000
#define TN (T_STEPS*NN)   // 400000
#define TE (T_STEPS*EE)   // 6400000

typedef unsigned int uint;
typedef unsigned short ushort;
typedef unsigned long long u64;
typedef __attribute__((ext_vector_type(8))) short short8;
typedef __attribute__((ext_vector_type(4))) float f32x4;

__device__ __forceinline__ float sigf(float x){ return 1.0f/(1.0f+expf(-x)); }
__device__ __forceinline__ ushort f2b(float f){
  uint x = __float_as_uint(f);
  uint r = (x + 0x7fffu + ((x>>16)&1u)) >> 16;
  return (ushort)r;
}
__device__ __forceinline__ float b2f(ushort u){ return __uint_as_float(((uint)u)<<16); }

__device__ __forceinline__ void gload16(const ushort* g, ushort* l){
  __builtin_amdgcn_global_load_lds(
      (const __attribute__((address_space(1))) void*)g,
      (__attribute__((address_space(3))) void*)l, 16, 0, 0);
}

// stage ROWS x 64 bf16 tile into LDS (pre-swizzled source, linear dest)
template<int ROWS>
__device__ __forceinline__ void stage_tile(const ushort* base, int ld, int rowclamp,
                                           ushort* lds, int lane, int wid){
  constexpr int ITERS = ROWS/32;
#pragma unroll
  for (int i=0;i<ITERS;i++){
    int lin = i*256 + wid*64 + lane;
    int row = lin>>3, s = lin&7;
    int gr = row; if (gr > rowclamp) gr = rowclamp;
    const ushort* gp = base + (size_t)gr*ld + ((s ^ (row&7))<<3);
    gload16(gp, lds + (size_t)(i*256 + wid*64)*8);
  }
}

__device__ __forceinline__ short8 fragld(const ushort* lds, int R, int kk, int lane){
  int slot = (kk*4 + (lane>>4)) ^ (R&7);
  return *(const short8*)&lds[R*64 + slot*8];
}

struct Seg { const ushort* p; int ld; long ts; int w; };

// ================= generic bf16 MFMA GEMM (128x128 tile, 3-seg A, batched t) ======
__global__ __launch_bounds__(256,2) void gemm_bf(
    Seg s0, Seg s1, Seg s2,
    const ushort* __restrict__ W, int K2, long Wts,
    const float* __restrict__ bias, int act,
    const ushort* __restrict__ addp, int ldad, long adts,
    float* __restrict__ C32, int ldc, long c32ts,
    ushort* __restrict__ C16, int ldb, long c16ts,
    int Nrow, int NOvalid)
{
  __shared__ __align__(16) ushort As[8192];
  __shared__ __align__(16) ushort Bs[8192];
  const int t    = blockIdx.z;
  const int tid  = threadIdx.x;
  const int lane = tid & 63;
  const int wid  = __builtin_amdgcn_readfirstlane(tid >> 6);
  const int brow = blockIdx.x*128;
  const int bcol = blockIdx.y*128;
  const int wr = wid>>1, wc = wid&1;

  f32x4 acc[4][4];
#pragma unroll
  for(int m=0;m<4;m++)
#pragma unroll
    for(int n=0;n<4;n++) acc[m][n] = (f32x4){0.f,0.f,0.f,0.f};

  const int nk = K2 >> 6;
  for (int kt=0; kt<nk; ++kt){
    int col0 = kt*64;
    const ushort* ab; int ald;
    if (col0 < s0.w){ ab = s0.p + (size_t)t*s0.ts + col0; ald = s0.ld; }
    else if (col0 < s0.w + s1.w){ ab = s1.p + (size_t)t*s1.ts + (col0 - s0.w); ald = s1.ld; }
    else { ab = s2.p + (size_t)t*s2.ts + (col0 - s0.w - s1.w); ald = s2.ld; }
    stage_tile<128>(ab + (size_t)brow*ald, ald, Nrow-1-brow, As, lane, wid);
    stage_tile<128>(W + (size_t)t*Wts + (size_t)bcol*K2 + col0, K2, 1<<30, Bs, lane, wid);
    __syncthreads();
#pragma unroll
    for (int kk=0;kk<2;kk++){
      short8 a[4], b[4];
#pragma unroll
      for (int m=0;m<4;m++) a[m] = fragld(As, wr*64 + m*16 + (lane&15), kk, lane);
#pragma unroll
      for (int n=0;n<4;n++) b[n] = fragld(Bs, wc*64 + n*16 + (lane&15), kk, lane);
#pragma unroll
      for (int m=0;m<4;m++)
#pragma unroll
        for (int n=0;n<4;n++)
          acc[m][n] = __builtin_amdgcn_mfma_f32_16x16x32_bf16(a[m], b[n], acc[m][n], 0,0,0);
    }
    __syncthreads();
  }
  const int rbase = brow + wr*64 + (lane>>4)*4;
  const int cbase = bcol + wc*64 + (lane&15);
#pragma unroll
  for (int m=0;m<4;m++){
#pragma unroll
    for (int q=0;q<4;q++){
      int r = rbase + m*16 + q;
      if (r >= Nrow) continue;
#pragma unroll
      for (int n=0;n<4;n++){
        int c = cbase + n*16;
        if (c >= NOvalid) continue;
        float v = acc[m][n][q];
        if (addp) v += b2f(addp[(size_t)t*adts + (size_t)r*ldad + c]);
        if (bias) v += bias[c];
        if (act==1) v = fmaxf(v, 0.f);
        if (C32) C32[(size_t)t*c32ts + (size_t)r*ldc + c] = v;
        if (C16) C16[(size_t)t*c16ts + (size_t)r*ldb + c] = f2b(v);
      }
    }
  }
}

// ================= fused GRU GEMM: [z | cyh | h] @ Wgru^T -> gates -> h_new =======
__global__ __launch_bounds__(256,2) void gemm_gru(
    Seg s0, Seg s1, Seg s2,
    const ushort* __restrict__ W,                        // Wgru [1024][448]
    const float* __restrict__ bg,                        // [1024]
    const float* __restrict__ hin,                       // fp32 h_t
    float* __restrict__ hout, ushort* __restrict__ hbfo, // hbfo != s2.p (ping-pong!)
    int Nrow)
{
  __shared__ __align__(16) ushort As[8192];
  __shared__ __align__(16) ushort Bs[8192];
  const int tid  = threadIdx.x;
  const int lane = tid & 63;
  const int wid  = __builtin_amdgcn_readfirstlane(tid >> 6);
  const int brow = blockIdx.x*128;
  const int bcol = blockIdx.y*128;
  const int wr = wid>>1, wc = wid&1;
  const int K2 = 448;

  f32x4 acc[4][4];
#pragma unroll
  for(int m=0;m<4;m++)
#pragma unroll
    for(int n=0;n<4;n++) acc[m][n] = (f32x4){0.f,0.f,0.f,0.f};

  for (int kt=0; kt<7; ++kt){
    int col0 = kt*64;
    const ushort* ab; int ald;
    if (col0 < s0.w){ ab = s0.p + col0; ald = s0.ld; }
    else if (col0 < s0.w + s1.w){ ab = s1.p + (col0 - s0.w); ald = s1.ld; }
    else { ab = s2.p + (col0 - s0.w - s1.w); ald = s2.ld; }
    stage_tile<128>(ab + (size_t)brow*ald, ald, Nrow-1-brow, As, lane, wid);
    stage_tile<128>(W + (size_t)bcol*K2 + col0, K2, 1<<30, Bs, lane, wid);
    __syncthreads();
#pragma unroll
    for (int kk=0;kk<2;kk++){
      short8 a[4], b[4];
#pragma unroll
      for (int m=0;m<4;m++) a[m] = fragld(As, wr*64 + m*16 + (lane&15), kk, lane);
#pragma unroll
      for (int n=0;n<4;n++) b[n] = fragld(Bs, wc*64 + n*16 + (lane&15), kk, lane);
#pragma unroll
      for (int m=0;m<4;m++)
#pragma unroll
        for (int n=0;n<4;n++)
          acc[m][n] = __builtin_amdgcn_mfma_f32_16x16x32_bf16(a[m], b[n], acc[m][n], 0,0,0);
    }
    __syncthreads();
  }
  const int jj = lane&15;
  const int j  = blockIdx.y*32 + wc*16 + jj;       // hidden unit index
  const int rbase = brow + wr*64 + (lane>>4)*4;
  const int bcolw = bcol + wc*64;
  float bb[4];
#pragma unroll
  for (int n=0;n<4;n++) bb[n] = bg[bcolw + n*16 + jj];
#pragma unroll
  for (int m=0;m<4;m++){
#pragma unroll
    for (int q=0;q<4;q++){
      int r = rbase + m*16 + q;
      if (r >= Nrow) continue;
      float v0 = acc[m][0][q] + bb[0];
      float v1 = acc[m][1][q] + bb[1];
      float v2 = acc[m][2][q] + bb[2];
      float v3 = acc[m][3][q] + bb[3];
      float rg = sigf(v0), ug = sigf(v1);
      float ng = tanhf(v2 + rg*v3);
      float ho = hin[(size_t)r*256 + j];
      float hn = (1.f-ug)*ng + ug*ho;
      hout[(size_t)r*256 + j] = hn;
      hbfo[(size_t)r*256 + j] = f2b(hn);
    }
  }
}

// ================= fused outcome heads (batched over t) ==============
__global__ __launch_bounds__(256,2) void heads_k(
    const ushort* __restrict__ Az, long Ats,             // zbf_all, ld 128
    const ushort* __restrict__ W,                        // wocT [256][128]
    const float* __restrict__ o00b, const float* __restrict__ o10b,
    const float* __restrict__ w01, const float* __restrict__ b01,
    const float* __restrict__ w11, const float* __restrict__ b11,
    float* __restrict__ y0out, long y0ts,
    float* __restrict__ y1out, long y1ts, int Nrow)
{
  __shared__ __align__(16) ushort As[4096];
  __shared__ __align__(16) ushort Bs[16384];
  __shared__ float shy[4][64];
  const int t    = blockIdx.z;
  const int tid  = threadIdx.x;
  const int lane = tid & 63;
  const int wid  = __builtin_amdgcn_readfirstlane(tid >> 6);
  const int brow = blockIdx.x*64;
  const ushort* A = Az + (size_t)t*Ats;

  f32x4 acc[4][4];
#pragma unroll
  for(int m=0;m<4;m++)
#pragma unroll
    for(int n=0;n<4;n++) acc[m][n] = (f32x4){0.f,0.f,0.f,0.f};

  for (int kt=0; kt<2; ++kt){
    stage_tile<64>(A + (size_t)brow*128 + kt*64, 128, Nrow-1-brow, As, lane, wid);
    stage_tile<256>(W + kt*64, 128, 1<<30, Bs, lane, wid);
    __syncthreads();
#pragma unroll
    for (int kk=0;kk<2;kk++){
      short8 a[4], b[4];
#pragma unroll
      for (int m=0;m<4;m++) a[m] = fragld(As, m*16 + (lane&15), kk, lane);
#pragma unroll
      for (int n=0;n<4;n++) b[n] = fragld(Bs, wid*64 + n*16 + (lane&15), kk, lane);
#pragma unroll
      for (int m=0;m<4;m++)
#pragma unroll
        for (int n=0;n<4;n++)
          acc[m][n] = __builtin_amdgcn_mfma_f32_16x16x32_bf16(a[m], b[n], acc[m][n], 0,0,0);
    }
    __syncthreads();
  }
  float bb[4], ww[4];
#pragma unroll
  for (int n=0;n<4;n++){
    int c = wid*64 + n*16 + (lane&15);
    bb[n] = (c<128)? o00b[c] : o10b[c-128];
    ww[n] = (c<128)? w01[c]  : w11[c-128];
  }
#pragma unroll
  for (int m=0;m<4;m++){
#pragma unroll
    for (int q=0;q<4;q++){
      float p = 0.f;
#pragma unroll
      for (int n=0;n<4;n++) p += fmaxf(acc[m][n][q] + bb[n], 0.f) * ww[n];
#pragma unroll
      for (int o=1;o<16;o<<=1) p += __shfl_xor(p, o);
      if ((lane&15)==0) shy[wid][m*16 + (lane>>4)*4 + q] = p;
    }
  }
  __syncthreads();
  if (tid < 64){
    int r = brow + tid;
    if (r < Nrow){
      y0out[(size_t)t*y0ts + r] = shy[0][tid] + shy[1][tid] + b01[0];
      y1out[(size_t)t*y1ts + r] = shy[2][tid] + shy[3][tid] + b11[0];
    }
  }
}

// ================= fused propensity head (batched over t) ==============
__global__ __launch_bounds__(256,2) void ps_k(
    const ushort* __restrict__ Az, long Ats,             // zbf_all, ld 128
    const ushort* __restrict__ W,                        // ps1T [128][128]
    const float* __restrict__ psc, const float* __restrict__ psb,
    const float* __restrict__ W2, const float* __restrict__ b2,
    float* __restrict__ psout, long psts, int Nrow)
{
  __shared__ __align__(16) ushort As[8192];
  __shared__ __align__(16) ushort Bs[8192];
  __shared__ float sh0[2][128];
  __shared__ float sh1[2][128];
  const int t    = blockIdx.z;
  const int tid  = threadIdx.x;
  const int lane = tid & 63;
  const int wid  = __builtin_amdgcn_readfirstlane(tid >> 6);
  const int brow = blockIdx.x*128;
  const int wr = wid>>1, wc = wid&1;
  const ushort* A = Az + (size_t)t*Ats;

  f32x4 acc[4][4];
#pragma unroll
  for(int m=0;m<4;m++)
#pragma unroll
    for(int n=0;n<4;n++) acc[m][n] = (f32x4){0.f,0.f,0.f,0.f};

  for (int kt=0; kt<2; ++kt){
    stage_tile<128>(A + (size_t)brow*128 + kt*64, 128, Nrow-1-brow, As, lane, wid);
    stage_tile<128>(W + kt*64, 128, 1<<30, Bs, lane, wid);
    __syncthreads();
#pragma unroll
    for (int kk=0;kk<2;kk++){
      short8 a[4], b[4];
#pragma unroll
      for (int m=0;m<4;m++) a[m] = fragld(As, wr*64 + m*16 + (lane&15), kk, lane);
#pragma unroll
      for (int n=0;n<4;n++) b[n] = fragld(Bs, wc*64 + n*16 + (lane&15), kk, lane);
#pragma unroll
      for (int m=0;m<4;m++)
#pragma unroll
        for (int n=0;n<4;n++)
          acc[m][n] = __builtin_amdgcn_mfma_f32_16x16x32_bf16(a[m], b[n], acc[m][n], 0,0,0);
    }
    __syncthreads();
  }
  float sc[4], sb[4], w0_[4], w1_[4];
#pragma unroll
  for (int n=0;n<4;n++){
    int c = wc*64 + n*16 + (lane&15);
    bool ok = (c<100);
    sc[n] = ok? psc[c] : 0.f;
    sb[n] = ok? psb[c] : 0.f;
    w0_[n]= ok? W2[2*c] : 0.f;
    w1_[n]= ok? W2[2*c+1] : 0.f;
  }
#pragma unroll
  for (int m=0;m<4;m++){
#pragma unroll
    for (int q=0;q<4;q++){
      float a0=0.f, a1=0.f;
#pragma unroll
      for (int n=0;n<4;n++){
        float s = sigf(acc[m][n][q]*sc[n] + sb[n]);
        a0 += s*w0_[n]; a1 += s*w1_[n];
      }
#pragma unroll
      for (int o=1;o<16;o<<=1){ a0 += __shfl_xor(a0,o); a1 += __shfl_xor(a1,o); }
      if ((lane&15)==0){
        int rt = wr*64 + m*16 + (lane>>4)*4 + q;
        sh0[wc][rt] = a0; sh1[wc][rt] = a1;
      }
    }
  }
  __syncthreads();
  if (tid < 128){
    int r = brow + tid;
    if (r < Nrow){
      float l0 = sh0[0][tid]+sh0[1][tid]+b2[0];
      float l1 = sh1[0][tid]+sh1[1][tid]+b2[1];
      float mx = fmaxf(l0,l1);
      float e0 = expf(l0-mx), e1 = expf(l1-mx);
      float inv = 1.f/(e0+e1);
      psout[(size_t)t*psts + (size_t)r*2]   = e0*inv;
      psout[(size_t)t*psts + (size_t)r*2+1] = e1*inv;
    }
  }
}

// ================= CSR build =================
__global__ void count_k(const int* __restrict__ ei, const float* __restrict__ ewl,
                        u64* __restrict__ degcnt)
{
  int idx = blockIdx.x*256 + threadIdx.x;
  if (idx >= TE) return;
  int t = idx / EE;
  int e = idx - t*EE;
  const int* dst = ei + (size_t)t*2*EE + EE;
  int d = dst[e];
  u64 v = (1ULL<<40) | (u64)(uint)(sigf(ewl[idx]) * 1048576.0f);
  atomicAdd((unsigned long long*)&degcnt[t*NN + d], (unsigned long long)v);
}

__global__ void dinv_k(const u64* __restrict__ degcnt, int* __restrict__ cnt,
                       float* __restrict__ dnv, float* __restrict__ invd){
  int idx = blockIdx.x*256+threadIdx.x;
  if (idx>=TN) return;
  u64 tot = degcnt[idx];
  int c = (int)(tot>>40);
  float S = (float)(tot & ((1ULL<<40)-1)) * (1.f/1048576.f);
  float dv = S + 1.f;
  cnt[idx] = c;
  dnv[idx]  = rsqrtf(dv);
  invd[idx] = 1.f/dv;
}

__global__ void scan1_k(const int* __restrict__ in, int* __restrict__ outv,
                        int* __restrict__ partials, int n)
{
  __shared__ int sh[256];
  int base = blockIdx.x*1024;
  int tid = threadIdx.x;
  int v[4]; int s=0;
#pragma unroll
  for (int i=0;i<4;i++){ int idx=base+tid*4+i; v[i] = (idx<n)? in[idx]:0; s+=v[i]; }
  sh[tid]=s; __syncthreads();
  for (int o=1;o<256;o<<=1){
    int t2 = (tid>=o)? sh[tid-o]:0;
    __syncthreads();
    sh[tid]+=t2;
    __syncthreads();
  }
  int excl = sh[tid]-s;
#pragma unroll
  for (int i=0;i<4;i++){ int idx=base+tid*4+i; if(idx<n) outv[idx]=excl; excl+=v[i]; }
  if (tid==255) partials[blockIdx.x]=sh[255];
}

__global__ void scan2_k(int* p, int np){
  __shared__ int sh[256];
  __shared__ int run;
  int tid=threadIdx.x;
  if(tid==0) run=0;
  __syncthreads();
  for(int base=0;base<np;base+=256){
    int v = (base+tid<np)? p[base+tid]:0;
    sh[tid]=v; __syncthreads();
    for(int o=1;o<256;o<<=1){
      int t2 = (tid>=o)? sh[tid-o]:0;
      __syncthreads();
      sh[tid]+=t2;
      __syncthreads();
    }
    int incl=sh[tid];
    int r0=run;
    __syncthreads();
    if(base+tid<np) p[base+tid]=r0+incl-v;
    __syncthreads();
    if(tid==0) run = r0 + sh[255];
    __syncthreads();
  }
}

__global__ void scan3_k(int* __restrict__ offs, const int* __restrict__ parts,
                        int* __restrict__ cur, int n){
  int idx = blockIdx.x*256+threadIdx.x;
  if (idx==0) offs[n] = TE;
  if (idx<n){ int v = offs[idx] + parts[idx>>10]; offs[idx]=v; cur[idx]=v; }
}

__global__ void fill_k(const int* __restrict__ ei, const float* __restrict__ ewl,
                       const float* __restrict__ dnv, int* __restrict__ cur,
                       uint* __restrict__ epack)
{
  int idx = blockIdx.x*256 + threadIdx.x;
  if (idx >= TE) return;
  int t = idx / EE;
  int e = idx - t*EE;
  const int* srcp = ei + (size_t)t*2*EE;
  const int* dstp = srcp + EE;
  int s=srcp[e], d=dstp[e];
  float nr = dnv[t*NN+s] * sigf(ewl[idx]) * dnv[t*NN+d];
  uint nq = (uint)(nr*65535.f + 0.5f);
  int pos = atomicAdd(&cur[t*NN+d], 1);
  epack[pos] = (uint)s | (nq<<16);
}

// ================= GCN gather (batched over t) =================
// wave = 1 node; two 32-lane halves each cover a FULL 256B row via uint2,
// halves interleave over the edge list (j=o0+half, step 2); manual unroll 4
// -> 8 rows in flight per wave. Cross-half combine via shfl_xor(32).
__global__ __launch_bounds__(256) void gather_k(const int* __restrict__ offs,
    const uint* __restrict__ epack,
    const ushort* __restrict__ xwb, const float* __restrict__ invd,
    const float* __restrict__ gcb, ushort* __restrict__ rep)
{
  int t    = blockIdx.z;
  int node = blockIdx.x*4 + (threadIdx.x>>6);
  int lane = threadIdx.x & 63;
  int half = lane>>5, ll = lane&31;
  if (node >= NN) return;
  const int* offs_t = offs + (size_t)t*NN;
  const ushort* xw_t = xwb + (size_t)t*NN*128;
  int o0 = offs_t[node], o1 = offs_t[node+1];
  float a0=0.f, a1=0.f, a2=0.f, a3=0.f;

  int j = o0 + half;
  // unrolled: 4 edges per half per iter (8 rows in flight per wave)
  for (; j+6 < o1; j += 8){
    uint e0 = epack[j],   e1 = epack[j+2];
    uint e2 = epack[j+4], e3 = epack[j+6];
    uint2 v0 = ((const uint2*)(xw_t + (size_t)(e0&0xffff)*128))[ll];
    uint2 v1 = ((const uint2*)(xw_t + (size_t)(e1&0xffff)*128))[ll];
    uint2 v2 = ((const uint2*)(xw_t + (size_t)(e2&0xffff)*128))[ll];
    uint2 v3 = ((const uint2*)(xw_t + (size_t)(e3&0xffff)*128))[ll];
    float n0 = (float)(e0>>16), n1 = (float)(e1>>16);
    float n2 = (float)(e2>>16), n3 = (float)(e3>>16);
    a0 = fmaf(n0, b2f((ushort)(v0.x&0xffff)), a0);
    a1 = fmaf(n0, b2f((ushort)(v0.x>>16)),   a1);
    a2 = fmaf(n0, b2f((ushort)(v0.y&0xffff)), a2);
    a3 = fmaf(n0, b2f((ushort)(v0.y>>16)),   a3);
    a0 = fmaf(n1, b2f((ushort)(v1.x&0xffff)), a0);
    a1 = fmaf(n1, b2f((ushort)(v1.x>>16)),   a1);
    a2 = fmaf(n1, b2f((ushort)(v1.y&0xffff)), a2);
    a3 = fmaf(n1, b2f((ushort)(v1.y>>16)),   a3);
    a0 = fmaf(n2, b2f((ushort)(v2.x&0xffff)), a0);
    a1 = fmaf(n2, b2f((ushort)(v2.x>>16)),   a1);
    a2 = fmaf(n2, b2f((ushort)(v2.y&0xffff)), a2);
    a3 = fmaf(n2, b2f((ushort)(v2.y>>16)),   a3);
    a0 = fmaf(n3, b2f((ushort)(v3.x&0xffff)), a0);
    a1 = fmaf(n3, b2f((ushort)(v3.x>>16)),   a1);
    a2 = fmaf(n3, b2f((ushort)(v3.y&0xffff)), a2);
    a3 = fmaf(n3, b2f((ushort)(v3.y>>16)),   a3);
  }
  for (; j < o1; j += 2){
    uint e0 = epack[j];
    uint2 v0 = ((const uint2*)(xw_t + (size_t)(e0&0xffff)*128))[ll];
    float n0 = (float)(e0>>16);
    a0 = fmaf(n0, b2f((ushort)(v0.x&0xffff)), a0);
    a1 = fmaf(n0, b2f((ushort)(v0.x>>16)),   a1);
    a2 = fmaf(n0, b2f((ushort)(v0.y&0xffff)), a2);
    a3 = fmaf(n0, b2f((ushort)(v0.y>>16)),   a3);
  }
  // combine halves (both halves end with full sums)
  a0 += __shfl_xor(a0, 32);
  a1 += __shfl_xor(a1, 32);
  a2 += __shfl_xor(a2, 32);
  a3 += __shfl_xor(a3, 32);
  const float qs = 1.f/65535.f;
  a0 *= qs; a1 *= qs; a2 *= qs; a3 *= qs;
  // self-loop + bias + relu (cols 4ll .. 4ll+3)
  float sl = invd[(size_t)t*NN + node];
  uint2 us = ((const uint2*)(xw_t + (size_t)node*128))[ll];
  float4 gb = ((const float4*)(gcb + (size_t)t*128))[ll];
  a0 = fmaf(sl, b2f((ushort)(us.x&0xffff)), a0) + gb.x;
  a1 = fmaf(sl, b2f((ushort)(us.x>>16)),   a1) + gb.y;
  a2 = fmaf(sl, b2f((ushort)(us.y&0xffff)), a2) + gb.z;
  a3 = fmaf(sl, b2f((ushort)(us.y>>16)),   a3) + gb.w;
  a0 = fmaxf(a0,0.f); a1 = fmaxf(a1,0.f);
  a2 = fmaxf(a2,0.f); a3 = fmaxf(a3,0.f);
  if (half==0){
    uint pk0 = (uint)f2b(a0) | ((uint)f2b(a1)<<16);
    uint pk1 = (uint)f2b(a2) | ((uint)f2b(a3)<<16);
    ((uint2*)(rep + ((size_t)t*NN + node)*128))[ll] = make_uint2(pk0, pk1);
  }
}

// ================= weight/activation prep =================
__global__ void convT_k(ushort* __restrict__ dst, const float* __restrict__ src,
                        int O, int Osrc, int K, int Kp)
{
  int idx = blockIdx.x*256 + threadIdx.x;
  if (idx >= O*Kp) return;
  dst += (size_t)blockIdx.y * O * Kp;
  src += (size_t)blockIdx.y * K * Osrc;
  int o = idx / Kp, k = idx - o*Kp;
  float v = (k<K && o<Osrc) ? src[(size_t)k*Osrc + o] : 0.f;
  dst[idx] = f2b(v);
}

__global__ void woc_k(ushort* __restrict__ dst, const float* __restrict__ o00W,
                      const float* __restrict__ o10W)
{
  int idx = blockIdx.x*256 + threadIdx.x;
  if (idx >= 256*128) return;
  int o = idx >> 7, k = idx & 127;
  float v = (o<128) ? o00W[(size_t)k*128 + o] : o10W[(size_t)k*128 + (o-128)];
  dst[idx] = f2b(v);
}

__global__ void wgru_k(const float* __restrict__ Wih, const float* __restrict__ Whh,
                       const float* __restrict__ bih, const float* __restrict__ bhh,
                       ushort* __restrict__ Wg, float* __restrict__ bg)
{
  int idx = blockIdx.x*256 + threadIdx.x;
  if (idx >= 1024*448) return;
  int c = idx/448, k = idx - c*448;
  int G = c>>6, g = (c>>4)&3, jj = c&15;
  int j = G*16 + jj;
  float v = 0.f;
  if (k < 152){
    if      (g==0) v = Wih[(size_t)j*152 + k];
    else if (g==1) v = Wih[(size_t)(256+j)*152 + k];
    else if (g==2) v = Wih[(size_t)(512+j)*152 + k];
  } else if (k >= 192){
    int kk = k-192;
    if      (g==0) v = Whh[(size_t)j*256 + kk];
    else if (g==1) v = Whh[(size_t)(256+j)*256 + kk];
    else if (g==3) v = Whh[(size_t)(512+j)*256 + kk];
  }
  Wg[idx] = f2b(v);
  if (k==0){
    float b;
    if      (g==0) b = bih[j]     + bhh[j];
    else if (g==1) b = bih[256+j] + bhh[256+j];
    else if (g==2) b = bih[512+j];
    else           b = bhh[512+j];
    bg[c] = b;
  }
}

__global__ void misc_k(const float* __restrict__ ps1b, const float* __restrict__ bng,
                       const float* __restrict__ bnb,
                       float* __restrict__ psc, float* __restrict__ psb)
{
  int i = threadIdx.x;
  if (i<100){ float sc = bng[i]*rsqrtf(1.f+1e-5f); psc[i]=sc; psb[i]=ps1b[i]*sc+bnb[i]; }
  else if (i<128){ psc[i]=0.f; psb[i]=0.f; }
}

__global__ void xconv_k(ushort* __restrict__ dst, const float* __restrict__ src, long n4)
{
  long i = (long)blockIdx.x*256 + threadIdx.x;
  if (i >= n4) return;
  float4 v = ((const float4*)src)[i];
  uint lo = (uint)f2b(v.x) | ((uint)f2b(v.y)<<16);
  uint hi = (uint)f2b(v.z) | ((uint)f2b(v.w)<<16);
  ((uint2*)dst)[i] = make_uint2(lo, hi);
}

// fill cyh_all[g][0:64] = [c(8) | yh(16) | zeros(40)] for all g = t*NN+n
__global__ void cyh_k(ushort* __restrict__ cyh, const float* __restrict__ Cc,
                      const float* __restrict__ Yh)
{
  long gid = (long)blockIdx.x*256 + threadIdx.x;   // TN*64
  if (gid >= (long)TN*64) return;
  long g = gid >> 6; int l = (int)(gid & 63);
  float v = 0.f;
  if (l < 8)       v = Cc[g*8 + l];
  else if (l < 24) v = Yh[g*16 + (l-8)];
  cyh[g*64 + l] = f2b(v);
}

extern "C" void kernel_launch(void* const* d_in, const int* in_sizes, int n_in,
                              void* d_out_v, int out_size, void* d_ws, size_t ws_size,
                              hipStream_t stream)
{
  const float* X    = (const float*)d_in[0];
  const float* Cc   = (const float*)d_in[1];
  const float* Yh   = (const float*)d_in[2];
  const int*   EI   = (const int*)  d_in[3];
  const float* phiW = (const float*)d_in[4];  const float* phib = (const float*)d_in[5];
  const float* gcW  = (const float*)d_in[6];  const float* gcb  = (const float*)d_in[7];
  const float* ewl  = (const float*)d_in[8];
  const float* fuseW= (const float*)d_in[9];  const float* fuseb= (const float*)d_in[10];
  const float* o00W = (const float*)d_in[11]; const float* o00b = (const float*)d_in[12];
  const float* o10W = (const float*)d_in[13]; const float* o10b = (const float*)d_in[14];
  const float* o01W = (const float*)d_in[15]; const float* o01b = (const float*)d_in[16];
  const float* o11W = (const float*)d_in[17]; const float* o11b = (const float*)d_in[18];
  const float* ps1W = (const float*)d_in[19]; const float* ps1b = (const float*)d_in[20];
  const float* bng  = (const float*)d_in[21]; const float* bnb  = (const float*)d_in[22];
  const float* ps2W = (const float*)d_in[23]; const float* ps2b = (const float*)d_in[24];
  const float* Wih  = (const float*)d_in[25]; const float* Whh  = (const float*)d_in[26];
  const float* bih  = (const float*)d_in[27]; const float* bhh  = (const float*)d_in[28];
  float* out = (float*)d_out_v;

  char* wsb = (char*)d_ws;
  size_t off=0;
  auto alloc=[&](size_t bytes)->void*{
    void* p = wsb + off;
    off = (off + bytes + 255) & ~(size_t)255;
    return p;
  };
  u64*   degcnt= (u64*)  alloc((size_t)TN*8);
  int*   cnt   = (int*)  alloc((size_t)TN*4);
  int*   cur   = (int*)  alloc((size_t)TN*4);
  int*   offs  = (int*)  alloc(((size_t)TN+1)*4);
  float* dnv   = (float*)alloc((size_t)TN*4);
  float* invd  = (float*)alloc((size_t)TN*4);
  uint*  epack = (uint*) alloc((size_t)TE*4);
  int*   parts = (int*)  alloc(4096);
  ushort* Xb   = (ushort*)alloc((size_t)TN*128*2);   // -> rep_all after phi GEMM
  ushort* phiA = (ushort*)alloc((size_t)TN*256*2);   // -> zbf_all + cyh_all after pz
  ushort* xwb  = (ushort*)alloc((size_t)TN*128*2);
  ushort* pz   = (ushort*)alloc((size_t)TN*128*2);
  ushort* hbf0 = (ushort*)alloc((size_t)NN*256*2);   // bf16 h ping-pong
  ushort* hbf1 = (ushort*)alloc((size_t)NN*256*2);
  float*  hb   = (float*)alloc((size_t)NN*256*4);    // fp32 h (in-place safe)
  ushort* phiWt= (ushort*)alloc(256*128*2);
  ushort* gcWt = (ushort*)alloc((size_t)T_STEPS*128*256*2);
  ushort* WhT  = (ushort*)alloc(128*256*2);
  ushort* WrpT = (ushort*)alloc(128*384*2);
  ushort* Wgru = (ushort*)alloc((size_t)1024*448*2);
  float* bgru  = (float*)alloc(1024*4);
  ushort* wocT = (ushort*)alloc(256*128*2);
  ushort* ps1T = (ushort*)alloc(128*128*2);
  float* psc   = (float*)alloc(128*4);
  float* psb   = (float*)alloc(128*4);

  ushort* rep_all = Xb;                              // TN x 128 (alias)
  ushort* zbf     = phiA;                            // TN x 128 (alias)
  ushort* cyh     = phiA + (size_t)TN*128;           // TN x 64  (alias)

  hipMemsetAsync(degcnt, 0, (size_t)TN*8, stream);
  hipMemsetAsync(hb,   0, (size_t)NN*256*4, stream);
  hipMemsetAsync(hbf0, 0, (size_t)NN*256*2, stream);

  // --- prep ---
  misc_k<<<1,256,0,stream>>>(ps1b,bng,bnb,psc,psb);
  convT_k<<<dim3((256*128+255)/256,1),256,0,stream>>>(phiWt, phiW, 256,256,128,128);
  convT_k<<<dim3((128*256+255)/256,T_STEPS),256,0,stream>>>(gcWt, gcW, 128,128,256,256);
  convT_k<<<dim3((128*256+255)/256,1),256,0,stream>>>(WhT, fuseW, 128,128,256,256);
  convT_k<<<dim3((128*384+255)/256,1),256,0,stream>>>(WrpT, fuseW+256*128, 128,128,384,384);
  convT_k<<<dim3((128*128+255)/256,1),256,0,stream>>>(ps1T, ps1W, 128,100,128,128);
  wgru_k<<<(1024*448+255)/256,256,0,stream>>>(Wih,Whh,bih,bhh,Wgru,bgru);
  woc_k<<<(256*128+255)/256,256,0,stream>>>(wocT, o00W, o10W);
  xconv_k<<<(int)(((size_t)TN*128/4+255)/256),256,0,stream>>>(Xb, X, (long)TN*128/4);

  // --- CSR build ---
  count_k<<<(TE+255)/256,256,0,stream>>>(EI,ewl,degcnt);
  dinv_k<<<(TN+255)/256,256,0,stream>>>(degcnt,cnt,dnv,invd);
  scan1_k<<<(TN+1023)/1024,256,0,stream>>>(cnt,offs,parts,TN);
  scan2_k<<<1,256,0,stream>>>(parts,(TN+1023)/1024);
  scan3_k<<<(TN+255)/256,256,0,stream>>>(offs,parts,cur,TN);
  fill_k<<<(TE+255)/256,256,0,stream>>>(EI,ewl,dnv,cur,epack);

  const size_t zoff  = (size_t)2*TN;
  const size_t psoff = zoff + (size_t)TN*128;
  const size_t hoff  = psoff + (size_t)TN*2;
  constexpr int GX = (NN+127)/128;                 // 391
  const Seg S0 = {nullptr,0,0,0};

  // --- batched recurrence-free work ---
  // phi_all = relu(X_t @ phi_W + b)
  gemm_bf<<<dim3(GX,2,8),256,0,stream>>>(
    Seg{Xb,128,(long)NN*128,128}, S0, S0, phiWt,128,0, phib,1,
    nullptr,0,0, nullptr,0,0, phiA,256,(long)NN*256, NN,256);
  // xw_all = phi_all @ gc_W[t]
  gemm_bf<<<dim3(GX,1,8),256,0,stream>>>(
    Seg{phiA,256,(long)NN*256,256}, S0, S0, gcWt,256,(long)128*256, nullptr,0,
    nullptr,0,0, nullptr,0,0, xwb,128,(long)NN*128, NN,128);
  // rep_all (overwrites Xb region; phi GEMM already consumed Xb)
  gather_k<<<dim3(NN/4,1,8),256,0,stream>>>(offs, epack, xwb, invd, gcb, rep_all);
  // pz_all = [rep_all | phi_all] @ [Wr;Wp]  (single fp32 accum, one bf16 rounding)
  gemm_bf<<<dim3(GX,1,8),256,0,stream>>>(
    Seg{rep_all,128,(long)NN*128,128}, Seg{phiA,256,(long)NN*256,256}, S0,
    WrpT,384,0, nullptr,0,
    nullptr,0,0, nullptr,0,0, pz,128,(long)NN*128, NN,128);
  // cyh_all (overwrites upper phiA region; phi_all dead after pz)
  cyh_k<<<(int)(((long)TN*64+255)/256),256,0,stream>>>(cyh, Cc, Yh);

  // --- recurrent chain ---
  for (int t=0;t<T_STEPS;t++){
    const ushort* hbi = (t&1)? hbf1 : hbf0;
    ushort*       hbo = (t&1)? hbf0 : hbf1;
    float* hout = (t==T_STEPS-1)? (out+hoff) : hb;
    float* zt = out + zoff + (size_t)t*NN*128;
    ushort* zbt = zbf + (size_t)t*NN*128;
    // z = relu(h@Wh + pz_t + fuse_b) -> fp32 zt + bf16 zbf_t
    gemm_bf<<<dim3(GX,1,1),256,0,stream>>>(
      Seg{hbi,256,0,256}, S0, S0, WhT,256,0, fuseb,1,
      pz + (size_t)t*NN*128,128,0, zt,128,0, zbt,128,0, NN,128);
    // fused GRU -> h (fp32 in-place, bf16 ping-pong)
    gemm_gru<<<dim3(GX,8),256,0,stream>>>(
      Seg{zbt,128,0,128}, Seg{cyh + (size_t)t*NN*64,64,0,64}, Seg{hbi,256,0,256},
      Wgru, bgru, hb, hout, hbo, NN);
  }

  // --- batched heads ---
  heads_k<<<dim3((NN+63)/64,1,8),256,0,stream>>>(
    zbf,(long)NN*128, wocT, o00b,o10b, o01W,o01b, o11W,o11b,
    out + TN, (long)NN,     // y0
    out, (long)NN, NN);     // y1
  ps_k<<<dim3(GX,1,8),256,0,stream>>>(
    zbf,(long)NN*128, ps1T, psc,psb, ps2W,ps2b,
    out+psoff, (long)NN*2, NN);

  (void)in_sizes; (void)n_in; (void)out_size; (void)ws_size;
}